// Round 14
// baseline (8391.364 us; speedup 1.0000x reference)
//
#include <hip/hip_runtime.h>

// Problem constants
constexpr int B_ = 256;
constexpr int T_ = 128;
constexpr int F_ = 32;
constexpr int U_ = 512;   // U_ENC
constexpr int D_ = 512;
constexpr int A_ = 512;
constexpr int G_ = 2048;  // 4*D

// qT/zhT fine grid (fixed); s_tab coarse grid (runtime range, KS points)
constexpr int   NS_ = 2048;
constexpr float LO_ = -8.0f;
constexpr float IDT_ = 128.0f;    // spacing 1/128 over [-8,8)
constexpr int   KS_ = 64;

typedef short bf16x8 __attribute__((ext_vector_type(8)));
typedef _Float16 f16x8 __attribute__((ext_vector_type(8)));
typedef float f32x4 __attribute__((ext_vector_type(4)));

__device__ __forceinline__ float sigf(float x) {
    float t = __builtin_amdgcn_exp2f(-1.44269504089f * x);
    return __builtin_amdgcn_rcpf(1.0f + t);
}
__device__ __forceinline__ float tanh_fast(float x) {
    float t = __builtin_amdgcn_exp2f(-2.88539008178f * x);
    return 2.0f * __builtin_amdgcn_rcpf(1.0f + t) - 1.0f;
}
__device__ __forceinline__ float bflo(unsigned int u) { return __uint_as_float(u << 16); }
__device__ __forceinline__ float bfhi(unsigned int u) { return __uint_as_float(u & 0xffff0000u); }
__device__ __forceinline__ unsigned short f2bf(float x) {
    unsigned int u = __float_as_uint(x);
    u = (u + 0x7fffu + ((u >> 16) & 1u)) >> 16;
    return (unsigned short)u;
}

// ---------------------------------------------------------------------------
__global__ __launch_bounds__(256) void k_h0build(
    const float* __restrict__ W0, const float* __restrict__ b0,
    float* __restrict__ h0T) {
    int idx4 = blockIdx.x * 256 + threadIdx.x;
    int s = idx4 >> 7, kq = (idx4 & 127) * 4;
    float sv = LO_ + (float)s * (1.0f / IDT_);
    float4 o;
    float* po = &o.x;
    #pragma unroll
    for (int jj = 0; jj < 4; ++jj) {
        int k = kq + jj;
        float zi = sv * W0[k] + b0[k];
        float zg = sv * W0[1024 + k] + b0[1024 + k];
        float zo = sv * W0[1536 + k] + b0[1536 + k];
        float c0 = sigf(zi) * tanh_fast(zg);
        po[jj] = sigf(zo) * tanh_fast(c0);
    }
    *(float4*)(h0T + (size_t)s * D_ + kq) = o;
}

__global__ __launch_bounds__(256) void k_gates1(
    const float* __restrict__ z1T, const float* __restrict__ b1,
    float* __restrict__ h1c1T) {
    int idx4 = blockIdx.x * 256 + threadIdx.x;
    int s = idx4 >> 7, dq = (idx4 & 127) * 4;
    const float* z = z1T + (size_t)s * G_;
    float4 hv, cv;
    float* ph = &hv.x; float* pc = &cv.x;
    #pragma unroll
    for (int jj = 0; jj < 4; ++jj) {
        int d = dq + jj;
        float zi = z[d] + b1[d];
        float zg = z[1024 + d] + b1[1024 + d];
        float zo = z[1536 + d] + b1[1536 + d];
        float c1 = sigf(zi) * tanh_fast(zg);
        pc[jj] = c1;
        ph[jj] = sigf(zo) * tanh_fast(c1);
    }
    *(float4*)(h1c1T + (size_t)s * (2 * D_) + dq) = hv;
    *(float4*)(h1c1T + (size_t)s * (2 * D_) + D_ + dq) = cv;
}

__global__ __launch_bounds__(256) void k_xd(
    const float* __restrict__ inp, const float* __restrict__ Wd,
    const float* __restrict__ bd, float* __restrict__ xd) {
    int id = blockIdx.x * 256 + threadIdx.x;
    const float* row = inp + (size_t)id * F_;
    float s = 0.f;
    #pragma unroll
    for (int f = 0; f < F_; ++f) s += row[f] * Wd[f];
    xd[id] = s + bd[0];
}

// f32 -> bf16 (RNE), 8 elems/thread; grid = elems/2048
__global__ __launch_bounds__(256) void k_cvt_bf16(
    const float* __restrict__ src, unsigned short* __restrict__ dst) {
    size_t i = ((size_t)blockIdx.x * 256 + threadIdx.x) * 8;
    float4 a = *(const float4*)(src + i);
    float4 b = *(const float4*)(src + i + 4);
    float v[8] = {a.x, a.y, a.z, a.w, b.x, b.y, b.z, b.w};
    unsigned int pk[4];
    #pragma unroll
    for (int j = 0; j < 4; ++j) {
        unsigned int u0 = (unsigned int)f2bf(v[2 * j]);
        unsigned int u1 = (unsigned int)f2bf(v[2 * j + 1]);
        pk[j] = u0 | (u1 << 16);
    }
    *(uint4*)(dst + i) = make_uint4(pk[0], pk[1], pk[2], pk[3]);
}

// e2[row] = enc[row,:] . Wd2
__global__ __launch_bounds__(256) void k_e2(
    const float* __restrict__ enc, const float* __restrict__ Wd2,
    float* __restrict__ e2) {
    const int row = blockIdx.x * 4 + (threadIdx.x >> 6);
    const int lane = threadIdx.x & 63;
    const float* p = enc + (size_t)row * U_ + lane * 8;
    float4 a = *(const float4*)p;
    float4 c = *(const float4*)(p + 4);
    const float* w = Wd2 + lane * 8;
    float4 wa = *(const float4*)w;
    float4 wc = *(const float4*)(w + 4);
    float s = a.x*wa.x + a.y*wa.y + a.z*wa.z + a.w*wa.w
            + c.x*wc.x + c.y*wc.y + c.z*wc.z + c.w*wc.w;
    #pragma unroll
    for (int off = 32; off; off >>= 1) s += __shfl_xor(s, off);
    if (lane == 0) e2[row] = s;
}

// Sound bounds for xin
__global__ __launch_bounds__(256) void k_bounds(
    const float* __restrict__ xd, const float* __restrict__ e2,
    float* __restrict__ rng) {
    const int tid = threadIdx.x;
    float mnx = 1e30f, mxx = -1e30f, mne = 1e30f, mxe = -1e30f;
    for (int i = tid; i < B_ * T_; i += 256) {
        float a = xd[i]; mnx = fminf(mnx, a); mxx = fmaxf(mxx, a);
        float b = e2[i]; mne = fminf(mne, b); mxe = fmaxf(mxe, b);
    }
    #pragma unroll
    for (int off = 32; off; off >>= 1) {
        mnx = fminf(mnx, __shfl_xor(mnx, off));
        mxx = fmaxf(mxx, __shfl_xor(mxx, off));
        mne = fminf(mne, __shfl_xor(mne, off));
        mxe = fmaxf(mxe, __shfl_xor(mxe, off));
    }
    __shared__ float red[4][4];
    const int wave = tid >> 6;
    if ((tid & 63) == 0) {
        red[wave][0] = mnx; red[wave][1] = mxx; red[wave][2] = mne; red[wave][3] = mxe;
    }
    __syncthreads();
    if (tid == 0) {
        mnx = fminf(fminf(red[0][0], red[1][0]), fminf(red[2][0], red[3][0]));
        mxx = fmaxf(fmaxf(red[0][1], red[1][1]), fmaxf(red[2][1], red[3][1]));
        mne = fminf(fminf(red[0][2], red[1][2]), fminf(red[2][2], red[3][2]));
        mxe = fmaxf(fmaxf(red[0][3], red[1][3]), fmaxf(red[2][3], red[3][3]));
        float lo = mnx + fminf(0.f, mne) - 1e-3f;
        float hi = mxx + fmaxf(0.f, mxe) + 1e-3f;
        float step = (hi - lo) / (float)(KS_ - 1);
        rng[0] = lo;
        rng[1] = step;
        rng[2] = 1.0f / step;
    }
}

// WkT[a][u] = bf16(Wk[u][a])
__global__ __launch_bounds__(256) void k_wkT(
    const float* __restrict__ Wk, unsigned short* __restrict__ WkT) {
    int idx = blockIdx.x * 256 + threadIdx.x;
    int a = idx >> 7, u0 = (idx & 127) * 4;
    unsigned int lo = (unsigned int)f2bf(Wk[(size_t)(u0 + 0) * A_ + a])
                    | ((unsigned int)f2bf(Wk[(size_t)(u0 + 1) * A_ + a]) << 16);
    unsigned int hi = (unsigned int)f2bf(Wk[(size_t)(u0 + 2) * A_ + a])
                    | ((unsigned int)f2bf(Wk[(size_t)(u0 + 3) * A_ + a]) << 16);
    *(uint2*)(WkT + (size_t)a * U_ + u0) = make_uint2(lo, hi);
}

// Generic transpose+cvt: dst[n][k] = bf16(src[k][n]); grid (N/64, K/64)
__global__ __launch_bounds__(256) void k_wT(
    const float* __restrict__ src, unsigned short* __restrict__ dst,
    int K, int N) {
    __shared__ unsigned short tile[64][72];
    const int n0 = blockIdx.x * 64, k0 = blockIdx.y * 64;
    const int tid = threadIdx.x;
    #pragma unroll
    for (int p = 0; p < 4; ++p) {
        int kk = (tid >> 4) + p * 16;
        int nn4 = (tid & 15) * 4;
        float4 v = *(const float4*)(src + (size_t)(k0 + kk) * N + n0 + nn4);
        tile[nn4 + 0][kk] = f2bf(v.x);
        tile[nn4 + 1][kk] = f2bf(v.y);
        tile[nn4 + 2][kk] = f2bf(v.z);
        tile[nn4 + 3][kk] = f2bf(v.w);
    }
    __syncthreads();
    #pragma unroll
    for (int p = 0; p < 4; ++p) {
        int nn = (tid >> 4) + p * 16;
        int k4 = (tid & 15) * 4;
        uint2 v = *(const uint2*)&tile[nn][k4];
        *(uint2*)(dst + (size_t)(n0 + nn) * K + k0 + k4) = v;
    }
}

// encT[b][u][tp] = f16(enc[b][tp][u])
__global__ __launch_bounds__(256) void k_encT(
    const float* __restrict__ enc, _Float16* __restrict__ encT) {
    __shared__ _Float16 tile[128][136];
    const int b = blockIdx.x >> 2;
    const int u0 = (blockIdx.x & 3) * 128;
    const int tid = threadIdx.x;
    #pragma unroll
    for (int p = 0; p < 16; ++p) {
        int i = p * 256 + tid;
        int tp = i >> 5, u4 = (i & 31) * 4;
        float4 v = *(const float4*)(enc + ((size_t)(b * T_ + tp)) * U_ + u0 + u4);
        tile[u4 + 0][tp] = (_Float16)v.x;
        tile[u4 + 1][tp] = (_Float16)v.y;
        tile[u4 + 2][tp] = (_Float16)v.z;
        tile[u4 + 3][tp] = (_Float16)v.w;
    }
    __syncthreads();
    #pragma unroll
    for (int p = 0; p < 8; ++p) {
        int i = p * 256 + tid;
        int u = i >> 4, t8 = (i & 15) * 8;
        uint4 v = *(const uint4*)&tile[u][t8];
        *(uint4*)(encT + ((size_t)(b * U_ + u0 + u)) * T_ + t8) = v;
    }
}

// ---------------------------------------------------------------------------
// Generic bf16 MFMA GEMM, f32 out: C[M][ldc] = A[M][K] @ BT[N][K]^T.
__global__ __launch_bounds__(256) void k_mm(
    const unsigned short* __restrict__ A,
    const unsigned short* __restrict__ BT,
    float* __restrict__ C, int K, int ldc) {
    const int n0 = blockIdx.x * 128;
    const int m0 = blockIdx.y * 128;
    const int lane = threadIdx.x & 63, wave = threadIdx.x >> 6;
    const int wm = wave >> 1, wn = wave & 1;
    const int frow = lane & 15, koct = (lane >> 4) * 8;
    const unsigned short* Ab = A + (size_t)(m0 + wm * 64 + frow) * K + koct;
    const unsigned short* Bb = BT + (size_t)(n0 + wn * 64 + frow) * K + koct;
    f32x4 acc[4][4] = {};
    for (int ks = 0; ks < K / 32; ++ks) {
        bf16x8 a[4], bb[4];
        #pragma unroll
        for (int m = 0; m < 4; ++m) a[m] = *(const bf16x8*)(Ab + (size_t)m * 16 * K + ks * 32);
        #pragma unroll
        for (int n = 0; n < 4; ++n) bb[n] = *(const bf16x8*)(Bb + (size_t)n * 16 * K + ks * 32);
        #pragma unroll
        for (int m = 0; m < 4; ++m)
            #pragma unroll
            for (int n = 0; n < 4; ++n)
                acc[m][n] = __builtin_amdgcn_mfma_f32_16x16x32_bf16(a[m], bb[n], acc[m][n], 0, 0, 0);
    }
    #pragma unroll
    for (int m = 0; m < 4; ++m)
        #pragma unroll
        for (int n = 0; n < 4; ++n)
            #pragma unroll
            for (int reg = 0; reg < 4; ++reg) {
                int r = m0 + wm * 64 + m * 16 + (lane >> 4) * 4 + reg;
                int a = n0 + wn * 64 + n * 16 + (lane & 15);
                C[(size_t)r * ldc + a] = acc[m][n][reg];
            }
}

// ---------------------------------------------------------------------------
// ep MFMA GEMM (bf16 out)
__global__ __launch_bounds__(256) void k_epmm(
    const unsigned short* __restrict__ enc_bf,
    const unsigned short* __restrict__ WkT,
    unsigned short* __restrict__ ep_bf) {
    const int n0 = blockIdx.x * 128;
    const int m0 = blockIdx.y * 128;
    const int lane = threadIdx.x & 63, wave = threadIdx.x >> 6;
    const int wm = wave >> 1, wn = wave & 1;
    const int frow = lane & 15, koct = (lane >> 4) * 8;
    const unsigned short* Ab = enc_bf + ((size_t)(m0 + wm * 64 + frow)) * U_ + koct;
    const unsigned short* Bb = WkT + ((size_t)(n0 + wn * 64 + frow)) * U_ + koct;
    f32x4 acc[4][4] = {};
    for (int ks = 0; ks < 16; ++ks) {
        bf16x8 a[4], bb[4];
        #pragma unroll
        for (int m = 0; m < 4; ++m) a[m] = *(const bf16x8*)(Ab + (size_t)m * 16 * U_ + ks * 32);
        #pragma unroll
        for (int n = 0; n < 4; ++n) bb[n] = *(const bf16x8*)(Bb + (size_t)n * 16 * U_ + ks * 32);
        #pragma unroll
        for (int m = 0; m < 4; ++m)
            #pragma unroll
            for (int n = 0; n < 4; ++n)
                acc[m][n] = __builtin_amdgcn_mfma_f32_16x16x32_bf16(a[m], bb[n], acc[m][n], 0, 0, 0);
    }
    #pragma unroll
    for (int m = 0; m < 4; ++m)
        #pragma unroll
        for (int n = 0; n < 4; ++n)
            #pragma unroll
            for (int reg = 0; reg < 4; ++reg) {
                int r = m0 + wm * 64 + m * 16 + (lane >> 4) * 4 + reg;
                int a = n0 + wn * 64 + n * 16 + (lane & 15);
                ep_bf[(size_t)r * A_ + a] = f2bf(acc[m][n][reg]);
            }
}

// ---------------------------------------------------------------------------
// Score table on runtime grid
__global__ __launch_bounds__(256) void k_stab(
    const float* __restrict__ qT, const unsigned short* __restrict__ ep_bf,
    const float* __restrict__ v_att, const float* __restrict__ rng,
    float* __restrict__ s_tab) {
    const int b = blockIdx.x >> 4;
    const int tp0 = (blockIdx.x & 15) * 8;
    const int lane = threadIdx.x & 63, wave = threadIdx.x >> 6;
    const float glo = rng[0], gstep = rng[1];
    float e8[8][8];
    #pragma unroll
    for (int r = 0; r < 8; ++r) {
        uint4 ev = *(const uint4*)(ep_bf + ((size_t)(b * T_ + tp0 + r)) * A_ + lane * 8);
        e8[r][0] = bflo(ev.x); e8[r][1] = bfhi(ev.x);
        e8[r][2] = bflo(ev.y); e8[r][3] = bfhi(ev.y);
        e8[r][4] = bflo(ev.z); e8[r][5] = bfhi(ev.z);
        e8[r][6] = bflo(ev.w); e8[r][7] = bfhi(ev.w);
    }
    float v8[8];
    *(float4*)&v8[0] = *(const float4*)(v_att + lane * 8);
    *(float4*)&v8[4] = *(const float4*)(v_att + lane * 8 + 4);
    for (int kk = 0; kk < 16; ++kk) {
        const int k = wave * 16 + kk;
        const float x = glo + (float)k * gstep;
        float u = fminf(fmaxf((x - LO_) * IDT_, 0.0f), (float)NS_ - 1.001f);
        const int i0 = (int)u;
        const float fr = u - (float)i0;
        const float* qa = qT + (size_t)i0 * A_ + lane * 8;
        const float* qb = qa + A_;
        float q8[8];
        {
            float4 la0 = *(const float4*)(qa);
            float4 la1 = *(const float4*)(qa + 4);
            float4 lb0 = *(const float4*)(qb);
            float4 lb1 = *(const float4*)(qb + 4);
            q8[0] = la0.x + fr * (lb0.x - la0.x);
            q8[1] = la0.y + fr * (lb0.y - la0.y);
            q8[2] = la0.z + fr * (lb0.z - la0.z);
            q8[3] = la0.w + fr * (lb0.w - la0.w);
            q8[4] = la1.x + fr * (lb1.x - la1.x);
            q8[5] = la1.y + fr * (lb1.y - la1.y);
            q8[6] = la1.z + fr * (lb1.z - la1.z);
            q8[7] = la1.w + fr * (lb1.w - la1.w);
        }
        float s[8] = {};
        #pragma unroll
        for (int r = 0; r < 8; ++r)
            #pragma unroll
            for (int j = 0; j < 8; ++j)
                s[r] += tanh_fast(q8[j] + e8[r][j]) * v8[j];
        #pragma unroll
        for (int r = 0; r < 8; ++r) {
            float xsum = s[r];
            #pragma unroll
            for (int off = 32; off; off >>= 1) xsum += __shfl_xor(xsum, off);
            if (lane == 0) s_tab[((size_t)(b * T_ + tp0 + r)) * KS_ + k] = xsum;
        }
    }
}

// ---------------------------------------------------------------------------
// Full xin recurrence + softmax weight output
__global__ __launch_bounds__(64) void k_chain(
    const float* __restrict__ s_tab, const float* __restrict__ e2,
    const float* __restrict__ xd, const float* __restrict__ rng,
    float* __restrict__ xinA, unsigned int* __restrict__ w_h32) {
    const int b = blockIdx.x;
    const int lane = threadIdx.x;
    const float glo = rng[0], gistep = rng[2];
    const int tpA = 2 * lane, tpB = 2 * lane + 1;
    const float e20 = e2[b * T_ + tpA];
    const float e21 = e2[b * T_ + tpB];
    const float* st0 = s_tab + ((size_t)b * T_ + tpA) * KS_;
    const float* st1 = s_tab + ((size_t)b * T_ + tpB) * KS_;
    float xin = xd[b * T_];
    for (int t = 0; t < T_; ++t) {
        if (lane == 0) xinA[t * B_ + b] = xin;
        float u = (xin - glo) * gistep;
        u = fminf(fmaxf(u, 0.0f), (float)KS_ - 1.001f);
        int k0 = (int)u; float fr = u - (float)k0;
        float a0 = st0[k0], a1 = st0[k0 + 1];
        float c0 = st1[k0], c1 = st1[k0 + 1];
        float s0 = a0 + fr * (a1 - a0);
        float s1 = c0 + fr * (c1 - c0);
        float m = fmaxf(s0, s1);
        #pragma unroll
        for (int off = 32; off; off >>= 1) m = fmaxf(m, __shfl_xor(m, off));
        float ex0 = __builtin_amdgcn_exp2f(1.44269504089f * (s0 - m));
        float ex1 = __builtin_amdgcn_exp2f(1.44269504089f * (s1 - m));
        float num = ex0 * e20 + ex1 * e21;
        float den = ex0 + ex1;
        #pragma unroll
        for (int off = 32; off; off >>= 1) {
            num += __shfl_xor(num, off);
            den += __shfl_xor(den, off);
        }
        float rdn = __builtin_amdgcn_rcpf(den);
        union { _Float16 h[2]; unsigned int u32; } cv;
        cv.h[0] = (_Float16)(ex0 * rdn);
        cv.h[1] = (_Float16)(ex1 * rdn);
        w_h32[((size_t)b * T_ + t) * 64 + lane] = cv.u32;
        if (t + 1 < T_) xin = xd[b * T_ + t + 1] + num * rdn;
    }
}

// ---------------------------------------------------------------------------
// ctx MFMA GEMM (f16)
__global__ __launch_bounds__(256) void k_ctxmm(
    const _Float16* __restrict__ w_h, const _Float16* __restrict__ encT,
    unsigned short* __restrict__ ctx_bf) {
    const int b = blockIdx.x >> 2;
    const int n0 = (blockIdx.x & 3) * 128;
    const int lane = threadIdx.x & 63, wave = threadIdx.x >> 6;
    const int wm = wave >> 1, wn = wave & 1;
    const int frow = lane & 15, koct = (lane >> 4) * 8;
    const _Float16* Ab = w_h + ((size_t)b * T_ + wm * 64 + frow) * T_ + koct;
    const _Float16* Bb = encT + ((size_t)(b * U_ + n0 + wn * 64 + frow)) * T_ + koct;
    f32x4 acc[4][4] = {};
    #pragma unroll
    for (int ks = 0; ks < 4; ++ks) {
        f16x8 a[4], bb[4];
        #pragma unroll
        for (int m = 0; m < 4; ++m) a[m] = *(const f16x8*)(Ab + (size_t)m * 16 * T_ + ks * 32);
        #pragma unroll
        for (int n = 0; n < 4; ++n) bb[n] = *(const f16x8*)(Bb + (size_t)n * 16 * T_ + ks * 32);
        #pragma unroll
        for (int m = 0; m < 4; ++m)
            #pragma unroll
            for (int n = 0; n < 4; ++n)
                acc[m][n] = __builtin_amdgcn_mfma_f32_16x16x32_f16(a[m], bb[n], acc[m][n], 0, 0, 0);
    }
    #pragma unroll
    for (int m = 0; m < 4; ++m)
        #pragma unroll
        for (int n = 0; n < 4; ++n)
            #pragma unroll
            for (int reg = 0; reg < 4; ++reg) {
                int t = wm * 64 + m * 16 + (lane >> 4) * 4 + reg;
                int u = n0 + wn * 64 + n * 16 + (lane & 15);
                ctx_bf[((size_t)t * B_ + b) * U_ + u] = f2bf(acc[m][n][reg]);
            }
}

// ---------------------------------------------------------------------------
// zc2[tb][col] = (ctx_bf @ Wf2T)[tb][col] + lerp(zhT, xin[tb]) + bf[col], f16.
__global__ __launch_bounds__(256) void k_zc(
    const unsigned short* __restrict__ ctx_bf,
    const unsigned short* __restrict__ Wf2T, int ldb,
    const float* __restrict__ zhT, const float* __restrict__ xinA,
    const float* __restrict__ bfv, _Float16* __restrict__ zc2) {
    const int n0 = blockIdx.x * 128;
    const int m0 = blockIdx.y * 128;
    const int lane = threadIdx.x & 63, wave = threadIdx.x >> 6;
    const int wm = wave >> 1, wn = wave & 1;
    const int frow = lane & 15, koct = (lane >> 4) * 8;
    const unsigned short* Ab = ctx_bf + (size_t)(m0 + wm * 64 + frow) * 512 + koct;
    const unsigned short* Bb = Wf2T + (size_t)(n0 + wn * 64 + frow) * ldb + koct;
    f32x4 acc[4][4] = {};
    for (int ks = 0; ks < 16; ++ks) {
        bf16x8 a[4], bb[4];
        #pragma unroll
        for (int m = 0; m < 4; ++m) a[m] = *(const bf16x8*)(Ab + (size_t)m * 16 * 512 + ks * 32);
        #pragma unroll
        for (int n = 0; n < 4; ++n) bb[n] = *(const bf16x8*)(Bb + (size_t)n * 16 * ldb + ks * 32);
        #pragma unroll
        for (int m = 0; m < 4; ++m)
            #pragma unroll
            for (int n = 0; n < 4; ++n)
                acc[m][n] = __builtin_amdgcn_mfma_f32_16x16x32_bf16(a[m], bb[n], acc[m][n], 0, 0, 0);
    }
    #pragma unroll
    for (int m = 0; m < 4; ++m)
        #pragma unroll
        for (int reg = 0; reg < 4; ++reg) {
            const int r = m0 + wm * 64 + m * 16 + (lane >> 4) * 4 + reg;
            const float xv = xinA[r];
            float u = fminf(fmaxf((xv - LO_) * IDT_, 0.0f), (float)NS_ - 1.001f);
            const int i0 = (int)u;
            const float fr = u - (float)i0;
            const float* zh0 = zhT + (size_t)i0 * G_;
            const float* zh1 = zh0 + G_;
            #pragma unroll
            for (int n = 0; n < 4; ++n) {
                const int col = n0 + wn * 64 + n * 16 + (lane & 15);
                const float lo = zh0[col];
                const float val = acc[m][n][reg] + lo + fr * (zh1[col] - lo) + bfv[col];
                zc2[(size_t)r * G_ + col] = (_Float16)val;
            }
        }
}

// ---------------------------------------------------------------------------
// Persistent-rows final LSTM: ONE launch, 16 blocks x 1024 threads. Block owns
// 16 rows (i = 16*blk..+16) and ALL 512 d-cols; h in LDS, c in registers,
// UfT streamed from L2, zc2 streamed from HBM. Row-independent recurrence ->
// zero inter-block communication; 2 __syncthreads per step.
// Wave w owns d-slice [w*32, w*32+32): z-cols {g*512 + w*32 + sub*16 + cl}.
__global__ __launch_bounds__(1024) void k_ffull(
    const unsigned short* __restrict__ UfT, const _Float16* __restrict__ zc2,
    float* __restrict__ out) {
    __shared__ unsigned short hL[16][520];
    const int tid = threadIdx.x;
    const int lane = tid & 63, wave = tid >> 6;   // wave = d-slice 0..15
    const int blk = blockIdx.x;                   // rows 16*blk .. +16
    // zero h
    for (int idx = tid; idx < 16 * 520; idx += 1024) ((unsigned short*)hL)[idx] = 0;
    const int cl = lane & 15;           // A-row / B-col / C-col index
    const int koct = (lane >> 4) * 8;
    const int rowbase = (lane >> 4) * 4;
    // B pointers for 8 col-frags: cf = 2*g + sub
    const unsigned short* Bp[8];
    #pragma unroll
    for (int cf = 0; cf < 8; ++cf) {
        const int g = cf >> 1, sub = cf & 1;
        const int col = g * 512 + wave * 32 + sub * 16 + cl;
        Bp[cf] = UfT + (size_t)col * 512 + koct;
    }
    float c_reg[8] = {};                 // [sub*4 + reg]
    __syncthreads();
    for (int j = 0; j < T_; ++j) {
        f32x4 acc[8] = {};
        #pragma unroll 4
        for (int kf = 0; kf < 16; ++kf) {
            bf16x8 a = *(const bf16x8*)&hL[cl][kf * 32 + koct];
            #pragma unroll
            for (int cf = 0; cf < 8; ++cf) {
                bf16x8 b = *(const bf16x8*)(Bp[cf] + kf * 32);
                acc[cf] = __builtin_amdgcn_mfma_f32_16x16x32_bf16(a, b, acc[cf], 0, 0, 0);
            }
        }
        __syncthreads();   // all reads of h_j complete
        #pragma unroll
        for (int sub = 0; sub < 2; ++sub) {
            const int d = wave * 32 + sub * 16 + cl;
            #pragma unroll
            for (int reg = 0; reg < 4; ++reg) {
                const int row = rowbase + reg;
                const int i = blk * 16 + row;
                const size_t tb = (size_t)(i >> 1) * B_ + ((i & 1) << 7) + j;
                const _Float16* zcrow = zc2 + tb * G_;
                const float zi = acc[0 + sub][reg] + (float)zcrow[d];
                const float zf = acc[2 + sub][reg] + (float)zcrow[512 + d];
                const float zg = acc[4 + sub][reg] + (float)zcrow[1024 + d];
                const float zo = acc[6 + sub][reg] + (float)zcrow[1536 + d];
                const float cn = sigf(zf) * c_reg[sub * 4 + reg] + sigf(zi) * tanh_fast(zg);
                const float hn = sigf(zo) * tanh_fast(cn);
                c_reg[sub * 4 + reg] = cn;
                hL[row][d] = f2bf(hn);
                out[((size_t)i * T_ + j) * D_ + d] = hn;
            }
        }
        __syncthreads();   // h_{j+1} complete
    }
}

// ---------------------------------------------------------------------------
extern "C" void kernel_launch(void* const* d_in, const int* in_sizes, int n_in,
                              void* d_out, int out_size, void* d_ws, size_t ws_size,
                              hipStream_t stream) {
    const float* inputs = (const float*)d_in[0];
    const float* enc    = (const float*)d_in[1];
    const float* Wd     = (const float*)d_in[2];
    const float* bd     = (const float*)d_in[3];
    const float* W0     = (const float*)d_in[4];
    const float* b0     = (const float*)d_in[6];
    const float* W1     = (const float*)d_in[7];
    const float* b1     = (const float*)d_in[9];
    const float* Wq     = (const float*)d_in[10];
    const float* Wk     = (const float*)d_in[11];
    const float* v_att  = (const float*)d_in[12];
    const float* Wf     = (const float*)d_in[13];
    const float* Uf     = (const float*)d_in[14];
    const float* bf     = (const float*)d_in[15];
    float* out = (float*)d_out;

    float* ws = (float*)d_ws;
    // ---- layout (f32 slots). zc2 overlays all early-phase-dead buffers.
    _Float16* zc2 = (_Float16*)(ws);                       // 33,554,432 S (written late)
    unsigned short* enc_bf = (unsigned short*)(ws);        //  8,388,608 S
    unsigned short* ep_bf  = (unsigned short*)(ws + 8388608);   // 8,388,608
    _Float16*       encT_h = (_Float16*)(ws + 16777216);        // 8,388,608
    float* s_tab   = ws + 25165824;                             // 2,097,152
    _Float16* w_h  = (_Float16*)(ws + 27262976);                // 2,097,152
    float* qT      = ws + 29360128;                             // 1,048,576
    float* h0T     = ws + 30408704;                             // 1,048,576
    unsigned short* h0T_bf = (unsigned short*)(ws + 31457280);  //   524,288
    unsigned short* W1T    = (unsigned short*)(ws + 31981568);  //   524,288
    unsigned short* WqT    = (unsigned short*)(ws + 32505856);  //   262,144
    // ---- beyond zc2 region:
    unsigned short* ctx_bf = (unsigned short*)(ws + 33554432);  // 8,388,608 (live til k_zc)
    float* zhT     = ws + 41943040;                             // 4,194,304
    float* h1c1T   = ws + 46137344;                             // 2,097,152
    unsigned short* h1c1T_bf = (unsigned short*)(ws + 48234496);// 1,048,576
    unsigned short* WfT    = (unsigned short*)(ws + 49283072);  // 1,048,576 (Wf2T = +512)
    unsigned short* UfT    = (unsigned short*)(ws + 50331648);  //   524,288
    unsigned short* WkT    = (unsigned short*)(ws + 50855936);  //   131,072
    float* e2      = ws + 50987008;                             //    32,768
    float* xd      = ws + 51019776;                             //    32,768
    float* xinA    = ws + 51052544;                             //    32,768
    float* rng     = ws + 51085312;                             //        16
    // z1T (2048x2048 f32) aliases ctx_bf region (dead before k_ctxmm writes it)
    float* z1T = (float*)ctx_bf;

    // ---- one-time tables (MFMA GEMMs) & conversions
    k_h0build<<<dim3(NS_ * D_ / 1024), 256, 0, stream>>>(W0, b0, h0T);
    k_cvt_bf16<<<dim3(512), 256, 0, stream>>>(h0T, h0T_bf);
    k_wT<<<dim3(32, 8), 256, 0, stream>>>(W1, W1T, 512, G_);
    k_mm<<<dim3(16, 16), 256, 0, stream>>>(h0T_bf, W1T, z1T, 512, G_);
    k_gates1<<<dim3(NS_ * D_ / 1024), 256, 0, stream>>>(z1T, b1, h1c1T);
    k_cvt_bf16<<<dim3(1024), 256, 0, stream>>>(h1c1T, h1c1T_bf);
    k_wT<<<dim3(8, 16), 256, 0, stream>>>(Wq, WqT, 1024, A_);
    k_mm<<<dim3(4, 16), 256, 0, stream>>>(h1c1T_bf, WqT, qT, 1024, A_);
    k_wT<<<dim3(32, 16), 256, 0, stream>>>(Wf, WfT, 1024, G_);
    k_mm<<<dim3(16, 16), 256, 0, stream>>>(h1c1T_bf, WfT, zhT, 1024, G_);
    k_wT<<<dim3(32, 8), 256, 0, stream>>>(Uf, UfT, 512, G_);
    k_cvt_bf16<<<dim3(8192), 256, 0, stream>>>(enc, enc_bf);
    k_wkT<<<dim3(256), 256, 0, stream>>>(Wk, WkT);
    k_epmm<<<dim3(4, 256), 256, 0, stream>>>(enc_bf, WkT, ep_bf);
    k_encT<<<dim3(B_ * 4), 256, 0, stream>>>(enc, encT_h);
    k_xd<<<dim3(B_ * T_ / 256), 256, 0, stream>>>(inputs, Wd, bd, xd);
    k_e2<<<dim3(B_ * T_ / 4), 256, 0, stream>>>(enc, Wd + F_, e2);
    k_bounds<<<dim3(1), 256, 0, stream>>>(xd, e2, rng);

    // ---- decoder: score table -> scalar chain (+weights) -> ctx GEMM
    k_stab<<<dim3(B_ * 16), 256, 0, stream>>>(qT, ep_bf, v_att, rng, s_tab);
    k_chain<<<dim3(B_), 64, 0, stream>>>(s_tab, e2, xd, rng, xinA, (unsigned int*)w_h);
    k_ctxmm<<<dim3(B_ * 4), 256, 0, stream>>>(w_h, encT_h, ctx_bf);

    // ---- hoist ctx@Wf2 + zhT-interp + bf out of the recurrence (one GEMM)
    k_zc<<<dim3(16, 256), 256, 0, stream>>>(ctx_bf, WfT + 512, 1024, zhT, xinA,
                                            bf, zc2);

    // ---- final LSTM: single launch, row-independent persistent blocks
    k_ffull<<<dim3(16), 1024, 0, stream>>>(UfT, zc2, out);
}

// Round 15
// 1763.211 us; speedup vs baseline: 4.7591x; 4.7591x over previous
//
#include <hip/hip_runtime.h>

// Problem constants
constexpr int B_ = 256;
constexpr int T_ = 128;
constexpr int F_ = 32;
constexpr int U_ = 512;   // U_ENC
constexpr int D_ = 512;
constexpr int A_ = 512;
constexpr int G_ = 2048;  // 4*D

// qT/zhT fine grid (fixed); s_tab coarse grid (runtime range, KS points)
constexpr int   NS_ = 2048;
constexpr float LO_ = -8.0f;
constexpr float IDT_ = 128.0f;    // spacing 1/128 over [-8,8)
constexpr int   KS_ = 40;

typedef short bf16x8 __attribute__((ext_vector_type(8)));
typedef _Float16 f16x8 __attribute__((ext_vector_type(8)));
typedef float f32x4 __attribute__((ext_vector_type(4)));

__device__ __forceinline__ float sigf(float x) {
    float t = __builtin_amdgcn_exp2f(-1.44269504089f * x);
    return __builtin_amdgcn_rcpf(1.0f + t);
}
__device__ __forceinline__ float tanh_fast(float x) {
    float t = __builtin_amdgcn_exp2f(-2.88539008178f * x);
    return 2.0f * __builtin_amdgcn_rcpf(1.0f + t) - 1.0f;
}
__device__ __forceinline__ float bflo(unsigned int u) { return __uint_as_float(u << 16); }
__device__ __forceinline__ float bfhi(unsigned int u) { return __uint_as_float(u & 0xffff0000u); }
__device__ __forceinline__ unsigned short f2bf(float x) {
    unsigned int u = __float_as_uint(x);
    u = (u + 0x7fffu + ((u >> 16) & 1u)) >> 16;
    return (unsigned short)u;
}

// ---------------------------------------------------------------------------
__global__ __launch_bounds__(256) void k_h0build(
    const float* __restrict__ W0, const float* __restrict__ b0,
    float* __restrict__ h0T) {
    int idx4 = blockIdx.x * 256 + threadIdx.x;
    int s = idx4 >> 7, kq = (idx4 & 127) * 4;
    float sv = LO_ + (float)s * (1.0f / IDT_);
    float4 o;
    float* po = &o.x;
    #pragma unroll
    for (int jj = 0; jj < 4; ++jj) {
        int k = kq + jj;
        float zi = sv * W0[k] + b0[k];
        float zg = sv * W0[1024 + k] + b0[1024 + k];
        float zo = sv * W0[1536 + k] + b0[1536 + k];
        float c0 = sigf(zi) * tanh_fast(zg);
        po[jj] = sigf(zo) * tanh_fast(c0);
    }
    *(float4*)(h0T + (size_t)s * D_ + kq) = o;
}

__global__ __launch_bounds__(256) void k_gates1(
    const float* __restrict__ z1T, const float* __restrict__ b1,
    float* __restrict__ h1c1T) {
    int idx4 = blockIdx.x * 256 + threadIdx.x;
    int s = idx4 >> 7, dq = (idx4 & 127) * 4;
    const float* z = z1T + (size_t)s * G_;
    float4 hv, cv;
    float* ph = &hv.x; float* pc = &cv.x;
    #pragma unroll
    for (int jj = 0; jj < 4; ++jj) {
        int d = dq + jj;
        float zi = z[d] + b1[d];
        float zg = z[1024 + d] + b1[1024 + d];
        float zo = z[1536 + d] + b1[1536 + d];
        float c1 = sigf(zi) * tanh_fast(zg);
        pc[jj] = c1;
        ph[jj] = sigf(zo) * tanh_fast(c1);
    }
    *(float4*)(h1c1T + (size_t)s * (2 * D_) + dq) = hv;
    *(float4*)(h1c1T + (size_t)s * (2 * D_) + D_ + dq) = cv;
}

__global__ __launch_bounds__(256) void k_xd(
    const float* __restrict__ inp, const float* __restrict__ Wd,
    const float* __restrict__ bd, float* __restrict__ xd) {
    int id = blockIdx.x * 256 + threadIdx.x;
    const float* row = inp + (size_t)id * F_;
    float s = 0.f;
    #pragma unroll
    for (int f = 0; f < F_; ++f) s += row[f] * Wd[f];
    xd[id] = s + bd[0];
}

// f32 -> bf16 (RNE), 8 elems/thread; grid = elems/2048
__global__ __launch_bounds__(256) void k_cvt_bf16(
    const float* __restrict__ src, unsigned short* __restrict__ dst) {
    size_t i = ((size_t)blockIdx.x * 256 + threadIdx.x) * 8;
    float4 a = *(const float4*)(src + i);
    float4 b = *(const float4*)(src + i + 4);
    float v[8] = {a.x, a.y, a.z, a.w, b.x, b.y, b.z, b.w};
    unsigned int pk[4];
    #pragma unroll
    for (int j = 0; j < 4; ++j) {
        unsigned int u0 = (unsigned int)f2bf(v[2 * j]);
        unsigned int u1 = (unsigned int)f2bf(v[2 * j + 1]);
        pk[j] = u0 | (u1 << 16);
    }
    *(uint4*)(dst + i) = make_uint4(pk[0], pk[1], pk[2], pk[3]);
}

// e2[row] = enc[row,:] . Wd2
__global__ __launch_bounds__(256) void k_e2(
    const float* __restrict__ enc, const float* __restrict__ Wd2,
    float* __restrict__ e2) {
    const int row = blockIdx.x * 4 + (threadIdx.x >> 6);
    const int lane = threadIdx.x & 63;
    const float* p = enc + (size_t)row * U_ + lane * 8;
    float4 a = *(const float4*)p;
    float4 c = *(const float4*)(p + 4);
    const float* w = Wd2 + lane * 8;
    float4 wa = *(const float4*)w;
    float4 wc = *(const float4*)(w + 4);
    float s = a.x*wa.x + a.y*wa.y + a.z*wa.z + a.w*wa.w
            + c.x*wc.x + c.y*wc.y + c.z*wc.z + c.w*wc.w;
    #pragma unroll
    for (int off = 32; off; off >>= 1) s += __shfl_xor(s, off);
    if (lane == 0) e2[row] = s;
}

// Sound bounds for xin
__global__ __launch_bounds__(256) void k_bounds(
    const float* __restrict__ xd, const float* __restrict__ e2,
    float* __restrict__ rng) {
    const int tid = threadIdx.x;
    float mnx = 1e30f, mxx = -1e30f, mne = 1e30f, mxe = -1e30f;
    for (int i = tid; i < B_ * T_; i += 256) {
        float a = xd[i]; mnx = fminf(mnx, a); mxx = fmaxf(mxx, a);
        float b = e2[i]; mne = fminf(mne, b); mxe = fmaxf(mxe, b);
    }
    #pragma unroll
    for (int off = 32; off; off >>= 1) {
        mnx = fminf(mnx, __shfl_xor(mnx, off));
        mxx = fmaxf(mxx, __shfl_xor(mxx, off));
        mne = fminf(mne, __shfl_xor(mne, off));
        mxe = fmaxf(mxe, __shfl_xor(mxe, off));
    }
    __shared__ float red[4][4];
    const int wave = tid >> 6;
    if ((tid & 63) == 0) {
        red[wave][0] = mnx; red[wave][1] = mxx; red[wave][2] = mne; red[wave][3] = mxe;
    }
    __syncthreads();
    if (tid == 0) {
        mnx = fminf(fminf(red[0][0], red[1][0]), fminf(red[2][0], red[3][0]));
        mxx = fmaxf(fmaxf(red[0][1], red[1][1]), fmaxf(red[2][1], red[3][1]));
        mne = fminf(fminf(red[0][2], red[1][2]), fminf(red[2][2], red[3][2]));
        mxe = fmaxf(fmaxf(red[0][3], red[1][3]), fmaxf(red[2][3], red[3][3]));
        float lo = mnx + fminf(0.f, mne) - 1e-3f;
        float hi = mxx + fmaxf(0.f, mxe) + 1e-3f;
        float step = (hi - lo) / (float)(KS_ - 1);
        rng[0] = lo;
        rng[1] = step;
        rng[2] = 1.0f / step;
    }
}

// WkT[a][u] = bf16(Wk[u][a])
__global__ __launch_bounds__(256) void k_wkT(
    const float* __restrict__ Wk, unsigned short* __restrict__ WkT) {
    int idx = blockIdx.x * 256 + threadIdx.x;
    int a = idx >> 7, u0 = (idx & 127) * 4;
    unsigned int lo = (unsigned int)f2bf(Wk[(size_t)(u0 + 0) * A_ + a])
                    | ((unsigned int)f2bf(Wk[(size_t)(u0 + 1) * A_ + a]) << 16);
    unsigned int hi = (unsigned int)f2bf(Wk[(size_t)(u0 + 2) * A_ + a])
                    | ((unsigned int)f2bf(Wk[(size_t)(u0 + 3) * A_ + a]) << 16);
    *(uint2*)(WkT + (size_t)a * U_ + u0) = make_uint2(lo, hi);
}

// Generic transpose+cvt: dst[n][k] = bf16(src[k][n]); grid (N/64, K/64)
__global__ __launch_bounds__(256) void k_wT(
    const float* __restrict__ src, unsigned short* __restrict__ dst,
    int K, int N) {
    __shared__ unsigned short tile[64][72];
    const int n0 = blockIdx.x * 64, k0 = blockIdx.y * 64;
    const int tid = threadIdx.x;
    #pragma unroll
    for (int p = 0; p < 4; ++p) {
        int kk = (tid >> 4) + p * 16;
        int nn4 = (tid & 15) * 4;
        float4 v = *(const float4*)(src + (size_t)(k0 + kk) * N + n0 + nn4);
        tile[nn4 + 0][kk] = f2bf(v.x);
        tile[nn4 + 1][kk] = f2bf(v.y);
        tile[nn4 + 2][kk] = f2bf(v.z);
        tile[nn4 + 3][kk] = f2bf(v.w);
    }
    __syncthreads();
    #pragma unroll
    for (int p = 0; p < 4; ++p) {
        int nn = (tid >> 4) + p * 16;
        int k4 = (tid & 15) * 4;
        uint2 v = *(const uint2*)&tile[nn][k4];
        *(uint2*)(dst + (size_t)(n0 + nn) * K + k0 + k4) = v;
    }
}

// encT[b][u][tp] = f16(enc[b][tp][u]); ALSO writes enc_bf (bf16 linear copy).
__global__ __launch_bounds__(256) void k_encT(
    const float* __restrict__ enc, _Float16* __restrict__ encT,
    unsigned short* __restrict__ enc_bf) {
    __shared__ _Float16 tile[128][136];
    const int b = blockIdx.x >> 2;
    const int u0 = (blockIdx.x & 3) * 128;
    const int tid = threadIdx.x;
    #pragma unroll
    for (int p = 0; p < 16; ++p) {
        int i = p * 256 + tid;
        int tp = i >> 5, u4 = (i & 31) * 4;
        float4 v = *(const float4*)(enc + ((size_t)(b * T_ + tp)) * U_ + u0 + u4);
        tile[u4 + 0][tp] = (_Float16)v.x;
        tile[u4 + 1][tp] = (_Float16)v.y;
        tile[u4 + 2][tp] = (_Float16)v.z;
        tile[u4 + 3][tp] = (_Float16)v.w;
        unsigned int lo = (unsigned int)f2bf(v.x) | ((unsigned int)f2bf(v.y) << 16);
        unsigned int hi = (unsigned int)f2bf(v.z) | ((unsigned int)f2bf(v.w) << 16);
        *(uint2*)(enc_bf + ((size_t)(b * T_ + tp)) * U_ + u0 + u4) = make_uint2(lo, hi);
    }
    __syncthreads();
    #pragma unroll
    for (int p = 0; p < 8; ++p) {
        int i = p * 256 + tid;
        int u = i >> 4, t8 = (i & 15) * 8;
        uint4 v = *(const uint4*)&tile[u][t8];
        *(uint4*)(encT + ((size_t)(b * U_ + u0 + u)) * T_ + t8) = v;
    }
}

// ---------------------------------------------------------------------------
// Generic bf16 MFMA GEMM, f32 out: C[M][ldc] = A[M][K] @ BT[N][K]^T.
__global__ __launch_bounds__(256) void k_mm(
    const unsigned short* __restrict__ A,
    const unsigned short* __restrict__ BT,
    float* __restrict__ C, int K, int ldc) {
    const int n0 = blockIdx.x * 128;
    const int m0 = blockIdx.y * 128;
    const int lane = threadIdx.x & 63, wave = threadIdx.x >> 6;
    const int wm = wave >> 1, wn = wave & 1;
    const int frow = lane & 15, koct = (lane >> 4) * 8;
    const unsigned short* Ab = A + (size_t)(m0 + wm * 64 + frow) * K + koct;
    const unsigned short* Bb = BT + (size_t)(n0 + wn * 64 + frow) * K + koct;
    f32x4 acc[4][4] = {};
    for (int ks = 0; ks < K / 32; ++ks) {
        bf16x8 a[4], bb[4];
        #pragma unroll
        for (int m = 0; m < 4; ++m) a[m] = *(const bf16x8*)(Ab + (size_t)m * 16 * K + ks * 32);
        #pragma unroll
        for (int n = 0; n < 4; ++n) bb[n] = *(const bf16x8*)(Bb + (size_t)n * 16 * K + ks * 32);
        #pragma unroll
        for (int m = 0; m < 4; ++m)
            #pragma unroll
            for (int n = 0; n < 4; ++n)
                acc[m][n] = __builtin_amdgcn_mfma_f32_16x16x32_bf16(a[m], bb[n], acc[m][n], 0, 0, 0);
    }
    #pragma unroll
    for (int m = 0; m < 4; ++m)
        #pragma unroll
        for (int n = 0; n < 4; ++n)
            #pragma unroll
            for (int reg = 0; reg < 4; ++reg) {
                int r = m0 + wm * 64 + m * 16 + (lane >> 4) * 4 + reg;
                int a = n0 + wn * 64 + n * 16 + (lane & 15);
                C[(size_t)r * ldc + a] = acc[m][n][reg];
            }
}

// ---------------------------------------------------------------------------
// ep MFMA GEMM (bf16 out)
__global__ __launch_bounds__(256) void k_epmm(
    const unsigned short* __restrict__ enc_bf,
    const unsigned short* __restrict__ WkT,
    unsigned short* __restrict__ ep_bf) {
    const int n0 = blockIdx.x * 128;
    const int m0 = blockIdx.y * 128;
    const int lane = threadIdx.x & 63, wave = threadIdx.x >> 6;
    const int wm = wave >> 1, wn = wave & 1;
    const int frow = lane & 15, koct = (lane >> 4) * 8;
    const unsigned short* Ab = enc_bf + ((size_t)(m0 + wm * 64 + frow)) * U_ + koct;
    const unsigned short* Bb = WkT + ((size_t)(n0 + wn * 64 + frow)) * U_ + koct;
    f32x4 acc[4][4] = {};
    for (int ks = 0; ks < 16; ++ks) {
        bf16x8 a[4], bb[4];
        #pragma unroll
        for (int m = 0; m < 4; ++m) a[m] = *(const bf16x8*)(Ab + (size_t)m * 16 * U_ + ks * 32);
        #pragma unroll
        for (int n = 0; n < 4; ++n) bb[n] = *(const bf16x8*)(Bb + (size_t)n * 16 * U_ + ks * 32);
        #pragma unroll
        for (int m = 0; m < 4; ++m)
            #pragma unroll
            for (int n = 0; n < 4; ++n)
                acc[m][n] = __builtin_amdgcn_mfma_f32_16x16x32_bf16(a[m], bb[n], acc[m][n], 0, 0, 0);
    }
    #pragma unroll
    for (int m = 0; m < 4; ++m)
        #pragma unroll
        for (int n = 0; n < 4; ++n)
            #pragma unroll
            for (int reg = 0; reg < 4; ++reg) {
                int r = m0 + wm * 64 + m * 16 + (lane >> 4) * 4 + reg;
                int a = n0 + wn * 64 + n * 16 + (lane & 15);
                ep_bf[(size_t)r * A_ + a] = f2bf(acc[m][n][reg]);
            }
}

// ---------------------------------------------------------------------------
// Score table on runtime grid: s_tab[b][tp][k] = sum_a tanh(q(x_k)[a]+ep)*v[a]
__global__ __launch_bounds__(256) void k_stab(
    const float* __restrict__ qT, const unsigned short* __restrict__ ep_bf,
    const float* __restrict__ v_att, const float* __restrict__ rng,
    float* __restrict__ s_tab) {
    const int b = blockIdx.x >> 4;
    const int tp0 = (blockIdx.x & 15) * 8;
    const int lane = threadIdx.x & 63, wave = threadIdx.x >> 6;
    const float glo = rng[0], gstep = rng[1];
    float e8[8][8];
    #pragma unroll
    for (int r = 0; r < 8; ++r) {
        uint4 ev = *(const uint4*)(ep_bf + ((size_t)(b * T_ + tp0 + r)) * A_ + lane * 8);
        e8[r][0] = bflo(ev.x); e8[r][1] = bfhi(ev.x);
        e8[r][2] = bflo(ev.y); e8[r][3] = bfhi(ev.y);
        e8[r][4] = bflo(ev.z); e8[r][5] = bfhi(ev.z);
        e8[r][6] = bflo(ev.w); e8[r][7] = bfhi(ev.w);
    }
    float v8[8];
    *(float4*)&v8[0] = *(const float4*)(v_att + lane * 8);
    *(float4*)&v8[4] = *(const float4*)(v_att + lane * 8 + 4);
    for (int k = wave; k < KS_; k += 4) {
        const float x = glo + (float)k * gstep;
        float u = fminf(fmaxf((x - LO_) * IDT_, 0.0f), (float)NS_ - 1.001f);
        const int i0 = (int)u;
        const float fr = u - (float)i0;
        const float* qa = qT + (size_t)i0 * A_ + lane * 8;
        const float* qb = qa + A_;
        float q8[8];
        {
            float4 la0 = *(const float4*)(qa);
            float4 la1 = *(const float4*)(qa + 4);
            float4 lb0 = *(const float4*)(qb);
            float4 lb1 = *(const float4*)(qb + 4);
            q8[0] = la0.x + fr * (lb0.x - la0.x);
            q8[1] = la0.y + fr * (lb0.y - la0.y);
            q8[2] = la0.z + fr * (lb0.z - la0.z);
            q8[3] = la0.w + fr * (lb0.w - la0.w);
            q8[4] = la1.x + fr * (lb1.x - la1.x);
            q8[5] = la1.y + fr * (lb1.y - la1.y);
            q8[6] = la1.z + fr * (lb1.z - la1.z);
            q8[7] = la1.w + fr * (lb1.w - la1.w);
        }
        float s[8] = {};
        #pragma unroll
        for (int r = 0; r < 8; ++r)
            #pragma unroll
            for (int j = 0; j < 8; ++j)
                s[r] += tanh_fast(q8[j] + e8[r][j]) * v8[j];
        #pragma unroll
        for (int r = 0; r < 8; ++r) {
            float xsum = s[r];
            #pragma unroll
            for (int off = 32; off; off >>= 1) xsum += __shfl_xor(xsum, off);
            if (lane == 0) s_tab[((size_t)(b * T_ + tp0 + r)) * KS_ + k] = xsum;
        }
    }
}

// ---------------------------------------------------------------------------
// Full xin recurrence + softmax weight output
__global__ __launch_bounds__(64) void k_chain(
    const float* __restrict__ s_tab, const float* __restrict__ e2,
    const float* __restrict__ xd, const float* __restrict__ rng,
    float* __restrict__ xinA, unsigned int* __restrict__ w_h32) {
    const int b = blockIdx.x;
    const int lane = threadIdx.x;
    const float glo = rng[0], gistep = rng[2];
    const int tpA = 2 * lane, tpB = 2 * lane + 1;
    const float e20 = e2[b * T_ + tpA];
    const float e21 = e2[b * T_ + tpB];
    const float* st0 = s_tab + ((size_t)b * T_ + tpA) * KS_;
    const float* st1 = s_tab + ((size_t)b * T_ + tpB) * KS_;
    float xin = xd[b * T_];
    for (int t = 0; t < T_; ++t) {
        if (lane == 0) xinA[t * B_ + b] = xin;
        float u = (xin - glo) * gistep;
        u = fminf(fmaxf(u, 0.0f), (float)KS_ - 1.001f);
        int k0 = (int)u; float fr = u - (float)k0;
        float a0 = st0[k0], a1 = st0[k0 + 1];
        float c0 = st1[k0], c1 = st1[k0 + 1];
        float s0 = a0 + fr * (a1 - a0);
        float s1 = c0 + fr * (c1 - c0);
        float m = fmaxf(s0, s1);
        #pragma unroll
        for (int off = 32; off; off >>= 1) m = fmaxf(m, __shfl_xor(m, off));
        float ex0 = __builtin_amdgcn_exp2f(1.44269504089f * (s0 - m));
        float ex1 = __builtin_amdgcn_exp2f(1.44269504089f * (s1 - m));
        float num = ex0 * e20 + ex1 * e21;
        float den = ex0 + ex1;
        #pragma unroll
        for (int off = 32; off; off >>= 1) {
            num += __shfl_xor(num, off);
            den += __shfl_xor(den, off);
        }
        float rdn = __builtin_amdgcn_rcpf(den);
        union { _Float16 h[2]; unsigned int u32; } cv;
        cv.h[0] = (_Float16)(ex0 * rdn);
        cv.h[1] = (_Float16)(ex1 * rdn);
        w_h32[((size_t)b * T_ + t) * 64 + lane] = cv.u32;
        if (t + 1 < T_) xin = xd[b * T_ + t + 1] + num * rdn;
    }
}

// ---------------------------------------------------------------------------
// ctx MFMA GEMM (f16)
__global__ __launch_bounds__(256) void k_ctxmm(
    const _Float16* __restrict__ w_h, const _Float16* __restrict__ encT,
    unsigned short* __restrict__ ctx_bf) {
    const int b = blockIdx.x >> 2;
    const int n0 = (blockIdx.x & 3) * 128;
    const int lane = threadIdx.x & 63, wave = threadIdx.x >> 6;
    const int wm = wave >> 1, wn = wave & 1;
    const int frow = lane & 15, koct = (lane >> 4) * 8;
    const _Float16* Ab = w_h + ((size_t)b * T_ + wm * 64 + frow) * T_ + koct;
    const _Float16* Bb = encT + ((size_t)(b * U_ + n0 + wn * 64 + frow)) * T_ + koct;
    f32x4 acc[4][4] = {};
    #pragma unroll
    for (int ks = 0; ks < 4; ++ks) {
        f16x8 a[4], bb[4];
        #pragma unroll
        for (int m = 0; m < 4; ++m) a[m] = *(const f16x8*)(Ab + (size_t)m * 16 * T_ + ks * 32);
        #pragma unroll
        for (int n = 0; n < 4; ++n) bb[n] = *(const f16x8*)(Bb + (size_t)n * 16 * T_ + ks * 32);
        #pragma unroll
        for (int m = 0; m < 4; ++m)
            #pragma unroll
            for (int n = 0; n < 4; ++n)
                acc[m][n] = __builtin_amdgcn_mfma_f32_16x16x32_f16(a[m], bb[n], acc[m][n], 0, 0, 0);
    }
    #pragma unroll
    for (int m = 0; m < 4; ++m)
        #pragma unroll
        for (int n = 0; n < 4; ++n)
            #pragma unroll
            for (int reg = 0; reg < 4; ++reg) {
                int t = wm * 64 + m * 16 + (lane >> 4) * 4 + reg;
                int u = n0 + wn * 64 + n * 16 + (lane & 15);
                ctx_bf[((size_t)t * B_ + b) * U_ + u] = f2bf(acc[m][n][reg]);
            }
}

// ---------------------------------------------------------------------------
// zc2[tb][col] = (ctx_bf @ Wf2T)[tb][col] + lerp(zhT, xin[tb]) + bf[col], f16.
__global__ __launch_bounds__(256) void k_zc(
    const unsigned short* __restrict__ ctx_bf,
    const unsigned short* __restrict__ Wf2T, int ldb,
    const float* __restrict__ zhT, const float* __restrict__ xinA,
    const float* __restrict__ bfv, _Float16* __restrict__ zc2) {
    const int n0 = blockIdx.x * 128;
    const int m0 = blockIdx.y * 128;
    const int lane = threadIdx.x & 63, wave = threadIdx.x >> 6;
    const int wm = wave >> 1, wn = wave & 1;
    const int frow = lane & 15, koct = (lane >> 4) * 8;
    const unsigned short* Ab = ctx_bf + (size_t)(m0 + wm * 64 + frow) * 512 + koct;
    const unsigned short* Bb = Wf2T + (size_t)(n0 + wn * 64 + frow) * ldb + koct;
    f32x4 acc[4][4] = {};
    for (int ks = 0; ks < 16; ++ks) {
        bf16x8 a[4], bb[4];
        #pragma unroll
        for (int m = 0; m < 4; ++m) a[m] = *(const bf16x8*)(Ab + (size_t)m * 16 * 512 + ks * 32);
        #pragma unroll
        for (int n = 0; n < 4; ++n) bb[n] = *(const bf16x8*)(Bb + (size_t)n * 16 * ldb + ks * 32);
        #pragma unroll
        for (int m = 0; m < 4; ++m)
            #pragma unroll
            for (int n = 0; n < 4; ++n)
                acc[m][n] = __builtin_amdgcn_mfma_f32_16x16x32_bf16(a[m], bb[n], acc[m][n], 0, 0, 0);
    }
    #pragma unroll
    for (int m = 0; m < 4; ++m)
        #pragma unroll
        for (int reg = 0; reg < 4; ++reg) {
            const int r = m0 + wm * 64 + m * 16 + (lane >> 4) * 4 + reg;
            const float xv = xinA[r];
            float u = fminf(fmaxf((xv - LO_) * IDT_, 0.0f), (float)NS_ - 1.001f);
            const int i0 = (int)u;
            const float fr = u - (float)i0;
            const float* zh0 = zhT + (size_t)i0 * G_;
            const float* zh1 = zh0 + G_;
            #pragma unroll
            for (int n = 0; n < 4; ++n) {
                const int col = n0 + wn * 64 + n * 16 + (lane & 15);
                const float lo = zh0[col];
                const float val = acc[m][n][reg] + lo + fr * (zh1[col] - lo) + bfv[col];
                zc2[(size_t)r * G_ + col] = (_Float16)val;
            }
        }
}

// ---------------------------------------------------------------------------
// Final LSTM step (relaunched per j). K=512 (h only); ctx+zhT+bf pre-fused in
// zc2. Grid (32 d-tiles, 8 r-tiles), 256 threads (4 waves).
__global__ __launch_bounds__(256) void k_frec3(
    const unsigned short* __restrict__ hin, unsigned short* __restrict__ hout,
    const unsigned short* __restrict__ UfT, const _Float16* __restrict__ zc2,
    float* __restrict__ c_f, float* __restrict__ out, int j) {
    __shared__ unsigned short As[32][520];   // 33,280 B
    __shared__ float zs[32 * 68];            //  8,704 B
    const int tid = threadIdx.x;
    const int lane = tid & 63, wave = tid >> 6;
    const int wr = wave >> 1, wc = wave & 1;
    const int d0 = blockIdx.x * 16;
    const int r0 = blockIdx.y * 32;
    // ---- stage A: 32 rows x 512 (h), once
    #pragma unroll
    for (int p = 0; p < 8; ++p) {
        int idx = p * 256 + tid;
        int row = idx >> 6, seg = idx & 63;
        int k = seg * 8;
        uint4 v = *(const uint4*)(hin + (size_t)(r0 + row) * 512 + k);
        *(uint4*)&As[row][k] = v;
    }
    __syncthreads();
    // ---- MFMA: wave owns rows [16wr,+16) x z-cols [32wc,+32)
    const int arow = 16 * wr + (lane & 15);
    const int koct = (lane >> 4) * 8;
    const int cl = lane & 15;
    const unsigned short* Bp0 = UfT + ((size_t)(((2 * wc) << 9) + d0 + cl)) * 512;
    const unsigned short* Bp1 = UfT + ((size_t)(((2 * wc + 1) << 9) + d0 + cl)) * 512;
    f32x4 acc0 = {0.f, 0.f, 0.f, 0.f};
    f32x4 acc1 = {0.f, 0.f, 0.f, 0.f};
    #pragma unroll
    for (int kc = 0; kc < 8; ++kc) {
        #pragma unroll
        for (int ks = 0; ks < 2; ++ks) {
            const int kw = kc * 64 + ks * 32 + koct;
            bf16x8 af = *(const bf16x8*)&As[arow][kw];
            bf16x8 b0 = *(const bf16x8*)(Bp0 + kw);
            bf16x8 b1 = *(const bf16x8*)(Bp1 + kw);
            acc0 = __builtin_amdgcn_mfma_f32_16x16x32_bf16(af, b0, acc0, 0, 0, 0);
            acc1 = __builtin_amdgcn_mfma_f32_16x16x32_bf16(af, b1, acc1, 0, 0, 0);
        }
    }
    // ---- spill z to LDS
    {
        const int srow = 16 * wr + (lane >> 4) * 4;
        const int scol = 32 * wc + (lane & 15);
        #pragma unroll
        for (int reg = 0; reg < 4; ++reg) {
            zs[(srow + reg) * 68 + scol] = acc0[reg];
            zs[(srow + reg) * 68 + scol + 16] = acc1[reg];
        }
    }
    __syncthreads();
    // ---- fused gate epilogue
    #pragma unroll
    for (int p = 0; p < 2; ++p) {
        const int it = p * 256 + tid;
        const int r = it >> 4, dd = it & 15;
        const int i = r0 + r, d = d0 + dd;
        const size_t tb = (size_t)(i >> 1) * B_ + ((i & 1) << 7) + j;
        const _Float16* zcrow = zc2 + tb * G_;
        float zg4[4];
        zg4[0] = zs[r * 68 + dd]      + (float)zcrow[d];
        zg4[1] = zs[r * 68 + 16 + dd] + (float)zcrow[512 + d];
        zg4[2] = zs[r * 68 + 32 + dd] + (float)zcrow[1024 + d];
        zg4[3] = zs[r * 68 + 48 + dd] + (float)zcrow[1536 + d];
        const float co = c_f[(size_t)i * D_ + d];
        const float cn = sigf(zg4[1]) * co + sigf(zg4[0]) * tanh_fast(zg4[2]);
        const float hn = sigf(zg4[3]) * tanh_fast(cn);
        c_f[(size_t)i * D_ + d] = cn;
        hout[(size_t)i * D_ + d] = f2bf(hn);
        out[((size_t)i * T_ + j) * D_ + d] = hn;
    }
}

// ---------------------------------------------------------------------------
extern "C" void kernel_launch(void* const* d_in, const int* in_sizes, int n_in,
                              void* d_out, int out_size, void* d_ws, size_t ws_size,
                              hipStream_t stream) {
    const float* inputs = (const float*)d_in[0];
    const float* enc    = (const float*)d_in[1];
    const float* Wd     = (const float*)d_in[2];
    const float* bd     = (const float*)d_in[3];
    const float* W0     = (const float*)d_in[4];
    const float* b0     = (const float*)d_in[6];
    const float* W1     = (const float*)d_in[7];
    const float* b1     = (const float*)d_in[9];
    const float* Wq     = (const float*)d_in[10];
    const float* Wk     = (const float*)d_in[11];
    const float* v_att  = (const float*)d_in[12];
    const float* Wf     = (const float*)d_in[13];
    const float* Uf     = (const float*)d_in[14];
    const float* bf     = (const float*)d_in[15];
    float* out = (float*)d_out;

    float* ws = (float*)d_ws;
    // ---- layout (f32 slots). zc2 overlays all early-phase-dead buffers.
    _Float16* zc2 = (_Float16*)(ws);                       // 33,554,432 S (written late)
    unsigned short* enc_bf = (unsigned short*)(ws);        //  8,388,608 S
    unsigned short* ep_bf  = (unsigned short*)(ws + 8388608);   // 8,388,608
    _Float16*       encT_h = (_Float16*)(ws + 16777216);        // 8,388,608
    float* s_tab   = ws + 25165824;                             // 2,097,152
    _Float16* w_h  = (_Float16*)(ws + 27262976);                // 2,097,152
    float* qT      = ws + 29360128;                             // 1,048,576
    float* h0T     = ws + 30408704;                             // 1,048,576
    unsigned short* h0T_bf = (unsigned short*)(ws + 31457280);  //   524,288
    unsigned short* W1T    = (unsigned short*)(ws + 31981568);  //   524,288
    unsigned short* WqT    = (unsigned short*)(ws + 32505856);  //   262,144
    // ---- beyond zc2 region:
    unsigned short* ctx_bf = (unsigned short*)(ws + 33554432);  // 8,388,608 (live til k_zc)
    float* zhT     = ws + 41943040;                             // 4,194,304
    float* h1c1T   = ws + 46137344;                             // 2,097,152
    unsigned short* h1c1T_bf = (unsigned short*)(ws + 48234496);// 1,048,576
    unsigned short* WfT    = (unsigned short*)(ws + 49283072);  // 1,048,576 (Wf2T = +512)
    unsigned short* UfT    = (unsigned short*)(ws + 50331648);  //   524,288
    unsigned short* WkT    = (unsigned short*)(ws + 50855936);  //   131,072
    float* e2      = ws + 50987008;                             //    32,768
    float* xd      = ws + 51019776;                             //    32,768
    float* xinA    = ws + 51052544;                             //    32,768
    unsigned short* h_bf = (unsigned short*)(ws + 51085312);    //   131,072 (2 bufs)
    float* c_f     = ws + 51216384;                             //   131,072
    float* rng     = ws + 51347456;                             //        16
    // z1T (2048x2048 f32) aliases ctx_bf region (dead before k_ctxmm writes it)
    float* z1T = (float*)ctx_bf;

    // ---- one-time tables (MFMA GEMMs) & conversions
    k_h0build<<<dim3(NS_ * D_ / 1024), 256, 0, stream>>>(W0, b0, h0T);
    k_cvt_bf16<<<dim3(512), 256, 0, stream>>>(h0T, h0T_bf);
    k_wT<<<dim3(32, 8), 256, 0, stream>>>(W1, W1T, 512, G_);
    k_mm<<<dim3(16, 16), 256, 0, stream>>>(h0T_bf, W1T, z1T, 512, G_);
    k_gates1<<<dim3(NS_ * D_ / 1024), 256, 0, stream>>>(z1T, b1, h1c1T);
    k_cvt_bf16<<<dim3(1024), 256, 0, stream>>>(h1c1T, h1c1T_bf);
    k_wT<<<dim3(8, 16), 256, 0, stream>>>(Wq, WqT, 1024, A_);
    k_mm<<<dim3(4, 16), 256, 0, stream>>>(h1c1T_bf, WqT, qT, 1024, A_);
    k_wT<<<dim3(32, 16), 256, 0, stream>>>(Wf, WfT, 1024, G_);
    k_mm<<<dim3(16, 16), 256, 0, stream>>>(h1c1T_bf, WfT, zhT, 1024, G_);
    k_wT<<<dim3(32, 8), 256, 0, stream>>>(Uf, UfT, 512, G_);
    k_encT<<<dim3(B_ * 4), 256, 0, stream>>>(enc, encT_h, enc_bf);
    k_wkT<<<dim3(256), 256, 0, stream>>>(Wk, WkT);
    k_epmm<<<dim3(4, 256), 256, 0, stream>>>(enc_bf, WkT, ep_bf);
    k_xd<<<dim3(B_ * T_ / 256), 256, 0, stream>>>(inputs, Wd, bd, xd);
    k_e2<<<dim3(B_ * T_ / 4), 256, 0, stream>>>(enc, Wd + F_, e2);
    k_bounds<<<dim3(1), 256, 0, stream>>>(xd, e2, rng);

    hipMemsetAsync(h_bf, 0, (size_t)B_ * D_ * sizeof(unsigned short), stream);
    hipMemsetAsync(c_f, 0, (size_t)B_ * D_ * sizeof(float), stream);

    // ---- decoder: score table -> scalar chain (+weights) -> ctx GEMM
    k_stab<<<dim3(B_ * 16), 256, 0, stream>>>(qT, ep_bf, v_att, rng, s_tab);
    k_chain<<<dim3(B_), 64, 0, stream>>>(s_tab, e2, xd, rng, xinA, (unsigned int*)w_h);
    k_ctxmm<<<dim3(B_ * 4), 256, 0, stream>>>(w_h, encT_h, ctx_bf);

    // ---- hoist ctx@Wf2 + zhT-interp + bf out of the recurrence (one GEMM)
    k_zc<<<dim3(16, 256), 256, 0, stream>>>(ctx_bf, WfT + 512, 1024, zhT, xinA,
                                            bf, zc2);

    // ---- final LSTM: 128 fused MFMA steps (K=512, h double-buffered)
    for (int j = 0; j < T_; ++j) {
        const unsigned short* hin = h_bf + (size_t)(j & 1) * (B_ * D_);
        unsigned short* hout = h_bf + (size_t)((j + 1) & 1) * (B_ * D_);
        k_frec3<<<dim3(32, 8), 256, 0, stream>>>(hin, hout, UfT, zc2, c_f, out, j);
    }
}

// Round 16
// 1731.927 us; speedup vs baseline: 4.8451x; 1.0181x over previous
//
#include <hip/hip_runtime.h>

// Problem constants
constexpr int B_ = 256;
constexpr int T_ = 128;
constexpr int F_ = 32;
constexpr int U_ = 512;   // U_ENC
constexpr int D_ = 512;
constexpr int A_ = 512;
constexpr int G_ = 2048;  // 4*D

// qT/zhT fine grid (fixed); s_tab coarse grid (runtime range, KS points)
constexpr int   NS_ = 2048;
constexpr float LO_ = -8.0f;
constexpr float IDT_ = 128.0f;    // spacing 1/128 over [-8,8)
constexpr int   KS_ = 32;

typedef short bf16x8 __attribute__((ext_vector_type(8)));
typedef _Float16 f16x8 __attribute__((ext_vector_type(8)));
typedef float f32x4 __attribute__((ext_vector_type(4)));

__device__ __forceinline__ float sigf(float x) {
    float t = __builtin_amdgcn_exp2f(-1.44269504089f * x);
    return __builtin_amdgcn_rcpf(1.0f + t);
}
__device__ __forceinline__ float tanh_fast(float x) {
    float t = __builtin_amdgcn_exp2f(-2.88539008178f * x);
    return 2.0f * __builtin_amdgcn_rcpf(1.0f + t) - 1.0f;
}
__device__ __forceinline__ float bflo(unsigned int u) { return __uint_as_float(u << 16); }
__device__ __forceinline__ float bfhi(unsigned int u) { return __uint_as_float(u & 0xffff0000u); }
__device__ __forceinline__ unsigned short f2bf(float x) {
    unsigned int u = __float_as_uint(x);
    u = (u + 0x7fffu + ((u >> 16) & 1u)) >> 16;
    return (unsigned short)u;
}

// ---------------------------------------------------------------------------
__global__ __launch_bounds__(256) void k_h0build(
    const float* __restrict__ W0, const float* __restrict__ b0,
    float* __restrict__ h0T) {
    int idx4 = blockIdx.x * 256 + threadIdx.x;
    int s = idx4 >> 7, kq = (idx4 & 127) * 4;
    float sv = LO_ + (float)s * (1.0f / IDT_);
    float4 o;
    float* po = &o.x;
    #pragma unroll
    for (int jj = 0; jj < 4; ++jj) {
        int k = kq + jj;
        float zi = sv * W0[k] + b0[k];
        float zg = sv * W0[1024 + k] + b0[1024 + k];
        float zo = sv * W0[1536 + k] + b0[1536 + k];
        float c0 = sigf(zi) * tanh_fast(zg);
        po[jj] = sigf(zo) * tanh_fast(c0);
    }
    *(float4*)(h0T + (size_t)s * D_ + kq) = o;
}

__global__ __launch_bounds__(256) void k_gates1(
    const float* __restrict__ z1T, const float* __restrict__ b1,
    float* __restrict__ h1c1T) {
    int idx4 = blockIdx.x * 256 + threadIdx.x;
    int s = idx4 >> 7, dq = (idx4 & 127) * 4;
    const float* z = z1T + (size_t)s * G_;
    float4 hv, cv;
    float* ph = &hv.x; float* pc = &cv.x;
    #pragma unroll
    for (int jj = 0; jj < 4; ++jj) {
        int d = dq + jj;
        float zi = z[d] + b1[d];
        float zg = z[1024 + d] + b1[1024 + d];
        float zo = z[1536 + d] + b1[1536 + d];
        float c1 = sigf(zi) * tanh_fast(zg);
        pc[jj] = c1;
        ph[jj] = sigf(zo) * tanh_fast(c1);
    }
    *(float4*)(h1c1T + (size_t)s * (2 * D_) + dq) = hv;
    *(float4*)(h1c1T + (size_t)s * (2 * D_) + D_ + dq) = cv;
}

__global__ __launch_bounds__(256) void k_xd(
    const float* __restrict__ inp, const float* __restrict__ Wd,
    const float* __restrict__ bd, float* __restrict__ xd) {
    int id = blockIdx.x * 256 + threadIdx.x;
    const float* row = inp + (size_t)id * F_;
    float s = 0.f;
    #pragma unroll
    for (int f = 0; f < F_; ++f) s += row[f] * Wd[f];
    xd[id] = s + bd[0];
}

// f32 -> bf16 (RNE), 8 elems/thread; grid = elems/2048
__global__ __launch_bounds__(256) void k_cvt_bf16(
    const float* __restrict__ src, unsigned short* __restrict__ dst) {
    size_t i = ((size_t)blockIdx.x * 256 + threadIdx.x) * 8;
    float4 a = *(const float4*)(src + i);
    float4 b = *(const float4*)(src + i + 4);
    float v[8] = {a.x, a.y, a.z, a.w, b.x, b.y, b.z, b.w};
    unsigned int pk[4];
    #pragma unroll
    for (int j = 0; j < 4; ++j) {
        unsigned int u0 = (unsigned int)f2bf(v[2 * j]);
        unsigned int u1 = (unsigned int)f2bf(v[2 * j + 1]);
        pk[j] = u0 | (u1 << 16);
    }
    *(uint4*)(dst + i) = make_uint4(pk[0], pk[1], pk[2], pk[3]);
}

// e2[row] = enc[row,:] . Wd2
__global__ __launch_bounds__(256) void k_e2(
    const float* __restrict__ enc, const float* __restrict__ Wd2,
    float* __restrict__ e2) {
    const int row = blockIdx.x * 4 + (threadIdx.x >> 6);
    const int lane = threadIdx.x & 63;
    const float* p = enc + (size_t)row * U_ + lane * 8;
    float4 a = *(const float4*)p;
    float4 c = *(const float4*)(p + 4);
    const float* w = Wd2 + lane * 8;
    float4 wa = *(const float4*)w;
    float4 wc = *(const float4*)(w + 4);
    float s = a.x*wa.x + a.y*wa.y + a.z*wa.z + a.w*wa.w
            + c.x*wc.x + c.y*wc.y + c.z*wc.z + c.w*wc.w;
    #pragma unroll
    for (int off = 32; off; off >>= 1) s += __shfl_xor(s, off);
    if (lane == 0) e2[row] = s;
}

// Sound bounds for xin
__global__ __launch_bounds__(256) void k_bounds(
    const float* __restrict__ xd, const float* __restrict__ e2,
    float* __restrict__ rng) {
    const int tid = threadIdx.x;
    float mnx = 1e30f, mxx = -1e30f, mne = 1e30f, mxe = -1e30f;
    for (int i = tid; i < B_ * T_; i += 256) {
        float a = xd[i]; mnx = fminf(mnx, a); mxx = fmaxf(mxx, a);
        float b = e2[i]; mne = fminf(mne, b); mxe = fmaxf(mxe, b);
    }
    #pragma unroll
    for (int off = 32; off; off >>= 1) {
        mnx = fminf(mnx, __shfl_xor(mnx, off));
        mxx = fmaxf(mxx, __shfl_xor(mxx, off));
        mne = fminf(mne, __shfl_xor(mne, off));
        mxe = fmaxf(mxe, __shfl_xor(mxe, off));
    }
    __shared__ float red[4][4];
    const int wave = tid >> 6;
    if ((tid & 63) == 0) {
        red[wave][0] = mnx; red[wave][1] = mxx; red[wave][2] = mne; red[wave][3] = mxe;
    }
    __syncthreads();
    if (tid == 0) {
        mnx = fminf(fminf(red[0][0], red[1][0]), fminf(red[2][0], red[3][0]));
        mxx = fmaxf(fmaxf(red[0][1], red[1][1]), fmaxf(red[2][1], red[3][1]));
        mne = fminf(fminf(red[0][2], red[1][2]), fminf(red[2][2], red[3][2]));
        mxe = fmaxf(fmaxf(red[0][3], red[1][3]), fmaxf(red[2][3], red[3][3]));
        float lo = mnx + fminf(0.f, mne) - 1e-3f;
        float hi = mxx + fmaxf(0.f, mxe) + 1e-3f;
        float step = (hi - lo) / (float)(KS_ - 1);
        rng[0] = lo;
        rng[1] = step;
        rng[2] = 1.0f / step;
    }
}

// WkT[a][u] = bf16(Wk[u][a])
__global__ __launch_bounds__(256) void k_wkT(
    const float* __restrict__ Wk, unsigned short* __restrict__ WkT) {
    int idx = blockIdx.x * 256 + threadIdx.x;
    int a = idx >> 7, u0 = (idx & 127) * 4;
    unsigned int lo = (unsigned int)f2bf(Wk[(size_t)(u0 + 0) * A_ + a])
                    | ((unsigned int)f2bf(Wk[(size_t)(u0 + 1) * A_ + a]) << 16);
    unsigned int hi = (unsigned int)f2bf(Wk[(size_t)(u0 + 2) * A_ + a])
                    | ((unsigned int)f2bf(Wk[(size_t)(u0 + 3) * A_ + a]) << 16);
    *(uint2*)(WkT + (size_t)a * U_ + u0) = make_uint2(lo, hi);
}

// Generic transpose+cvt: dst[n][k] = bf16(src[k][n]); grid (N/64, K/64)
__global__ __launch_bounds__(256) void k_wT(
    const float* __restrict__ src, unsigned short* __restrict__ dst,
    int K, int N) {
    __shared__ unsigned short tile[64][72];
    const int n0 = blockIdx.x * 64, k0 = blockIdx.y * 64;
    const int tid = threadIdx.x;
    #pragma unroll
    for (int p = 0; p < 4; ++p) {
        int kk = (tid >> 4) + p * 16;
        int nn4 = (tid & 15) * 4;
        float4 v = *(const float4*)(src + (size_t)(k0 + kk) * N + n0 + nn4);
        tile[nn4 + 0][kk] = f2bf(v.x);
        tile[nn4 + 1][kk] = f2bf(v.y);
        tile[nn4 + 2][kk] = f2bf(v.z);
        tile[nn4 + 3][kk] = f2bf(v.w);
    }
    __syncthreads();
    #pragma unroll
    for (int p = 0; p < 4; ++p) {
        int nn = (tid >> 4) + p * 16;
        int k4 = (tid & 15) * 4;
        uint2 v = *(const uint2*)&tile[nn][k4];
        *(uint2*)(dst + (size_t)(n0 + nn) * K + k0 + k4) = v;
    }
}

// encT[b][u][tp] = f16(enc[b][tp][u]); ALSO writes enc_bf (bf16 linear copy).
__global__ __launch_bounds__(256) void k_encT(
    const float* __restrict__ enc, _Float16* __restrict__ encT,
    unsigned short* __restrict__ enc_bf) {
    __shared__ _Float16 tile[128][136];
    const int b = blockIdx.x >> 2;
    const int u0 = (blockIdx.x & 3) * 128;
    const int tid = threadIdx.x;
    #pragma unroll
    for (int p = 0; p < 16; ++p) {
        int i = p * 256 + tid;
        int tp = i >> 5, u4 = (i & 31) * 4;
        float4 v = *(const float4*)(enc + ((size_t)(b * T_ + tp)) * U_ + u0 + u4);
        tile[u4 + 0][tp] = (_Float16)v.x;
        tile[u4 + 1][tp] = (_Float16)v.y;
        tile[u4 + 2][tp] = (_Float16)v.z;
        tile[u4 + 3][tp] = (_Float16)v.w;
        unsigned int lo = (unsigned int)f2bf(v.x) | ((unsigned int)f2bf(v.y) << 16);
        unsigned int hi = (unsigned int)f2bf(v.z) | ((unsigned int)f2bf(v.w) << 16);
        *(uint2*)(enc_bf + ((size_t)(b * T_ + tp)) * U_ + u0 + u4) = make_uint2(lo, hi);
    }
    __syncthreads();
    #pragma unroll
    for (int p = 0; p < 8; ++p) {
        int i = p * 256 + tid;
        int u = i >> 4, t8 = (i & 15) * 8;
        uint4 v = *(const uint4*)&tile[u][t8];
        *(uint4*)(encT + ((size_t)(b * U_ + u0 + u)) * T_ + t8) = v;
    }
}

// ---------------------------------------------------------------------------
// Generic bf16 MFMA GEMM, f32 out: C[M][ldc] = A[M][K] @ BT[N][K]^T.
__global__ __launch_bounds__(256) void k_mm(
    const unsigned short* __restrict__ A,
    const unsigned short* __restrict__ BT,
    float* __restrict__ C, int K, int ldc) {
    const int n0 = blockIdx.x * 128;
    const int m0 = blockIdx.y * 128;
    const int lane = threadIdx.x & 63, wave = threadIdx.x >> 6;
    const int wm = wave >> 1, wn = wave & 1;
    const int frow = lane & 15, koct = (lane >> 4) * 8;
    const unsigned short* Ab = A + (size_t)(m0 + wm * 64 + frow) * K + koct;
    const unsigned short* Bb = BT + (size_t)(n0 + wn * 64 + frow) * K + koct;
    f32x4 acc[4][4] = {};
    for (int ks = 0; ks < K / 32; ++ks) {
        bf16x8 a[4], bb[4];
        #pragma unroll
        for (int m = 0; m < 4; ++m) a[m] = *(const bf16x8*)(Ab + (size_t)m * 16 * K + ks * 32);
        #pragma unroll
        for (int n = 0; n < 4; ++n) bb[n] = *(const bf16x8*)(Bb + (size_t)n * 16 * K + ks * 32);
        #pragma unroll
        for (int m = 0; m < 4; ++m)
            #pragma unroll
            for (int n = 0; n < 4; ++n)
                acc[m][n] = __builtin_amdgcn_mfma_f32_16x16x32_bf16(a[m], bb[n], acc[m][n], 0, 0, 0);
    }
    #pragma unroll
    for (int m = 0; m < 4; ++m)
        #pragma unroll
        for (int n = 0; n < 4; ++n)
            #pragma unroll
            for (int reg = 0; reg < 4; ++reg) {
                int r = m0 + wm * 64 + m * 16 + (lane >> 4) * 4 + reg;
                int a = n0 + wn * 64 + n * 16 + (lane & 15);
                C[(size_t)r * ldc + a] = acc[m][n][reg];
            }
}

// Same but f16 output (for zhT table: halves k_zc's gather traffic).
__global__ __launch_bounds__(256) void k_mmh(
    const unsigned short* __restrict__ A,
    const unsigned short* __restrict__ BT,
    _Float16* __restrict__ C, int K, int ldc) {
    const int n0 = blockIdx.x * 128;
    const int m0 = blockIdx.y * 128;
    const int lane = threadIdx.x & 63, wave = threadIdx.x >> 6;
    const int wm = wave >> 1, wn = wave & 1;
    const int frow = lane & 15, koct = (lane >> 4) * 8;
    const unsigned short* Ab = A + (size_t)(m0 + wm * 64 + frow) * K + koct;
    const unsigned short* Bb = BT + (size_t)(n0 + wn * 64 + frow) * K + koct;
    f32x4 acc[4][4] = {};
    for (int ks = 0; ks < K / 32; ++ks) {
        bf16x8 a[4], bb[4];
        #pragma unroll
        for (int m = 0; m < 4; ++m) a[m] = *(const bf16x8*)(Ab + (size_t)m * 16 * K + ks * 32);
        #pragma unroll
        for (int n = 0; n < 4; ++n) bb[n] = *(const bf16x8*)(Bb + (size_t)n * 16 * K + ks * 32);
        #pragma unroll
        for (int m = 0; m < 4; ++m)
            #pragma unroll
            for (int n = 0; n < 4; ++n)
                acc[m][n] = __builtin_amdgcn_mfma_f32_16x16x32_bf16(a[m], bb[n], acc[m][n], 0, 0, 0);
    }
    #pragma unroll
    for (int m = 0; m < 4; ++m)
        #pragma unroll
        for (int n = 0; n < 4; ++n)
            #pragma unroll
            for (int reg = 0; reg < 4; ++reg) {
                int r = m0 + wm * 64 + m * 16 + (lane >> 4) * 4 + reg;
                int a = n0 + wn * 64 + n * 16 + (lane & 15);
                C[(size_t)r * ldc + a] = (_Float16)acc[m][n][reg];
            }
}

// ---------------------------------------------------------------------------
// ep MFMA GEMM (bf16 out)
__global__ __launch_bounds__(256) void k_epmm(
    const unsigned short* __restrict__ enc_bf,
    const unsigned short* __restrict__ WkT,
    unsigned short* __restrict__ ep_bf) {
    const int n0 = blockIdx.x * 128;
    const int m0 = blockIdx.y * 128;
    const int lane = threadIdx.x & 63, wave = threadIdx.x >> 6;
    const int wm = wave >> 1, wn = wave & 1;
    const int frow = lane & 15, koct = (lane >> 4) * 8;
    const unsigned short* Ab = enc_bf + ((size_t)(m0 + wm * 64 + frow)) * U_ + koct;
    const unsigned short* Bb = WkT + ((size_t)(n0 + wn * 64 + frow)) * U_ + koct;
    f32x4 acc[4][4] = {};
    for (int ks = 0; ks < 16; ++ks) {
        bf16x8 a[4], bb[4];
        #pragma unroll
        for (int m = 0; m < 4; ++m) a[m] = *(const bf16x8*)(Ab + (size_t)m * 16 * U_ + ks * 32);
        #pragma unroll
        for (int n = 0; n < 4; ++n) bb[n] = *(const bf16x8*)(Bb + (size_t)n * 16 * U_ + ks * 32);
        #pragma unroll
        for (int m = 0; m < 4; ++m)
            #pragma unroll
            for (int n = 0; n < 4; ++n)
                acc[m][n] = __builtin_amdgcn_mfma_f32_16x16x32_bf16(a[m], bb[n], acc[m][n], 0, 0, 0);
    }
    #pragma unroll
    for (int m = 0; m < 4; ++m)
        #pragma unroll
        for (int n = 0; n < 4; ++n)
            #pragma unroll
            for (int reg = 0; reg < 4; ++reg) {
                int r = m0 + wm * 64 + m * 16 + (lane >> 4) * 4 + reg;
                int a = n0 + wn * 64 + n * 16 + (lane & 15);
                ep_bf[(size_t)r * A_ + a] = f2bf(acc[m][n][reg]);
            }
}

// ---------------------------------------------------------------------------
// Score table on runtime grid: s_tab[b][tp][k] = sum_a tanh(q(x_k)[a]+ep)*v[a]
__global__ __launch_bounds__(256) void k_stab(
    const float* __restrict__ qT, const unsigned short* __restrict__ ep_bf,
    const float* __restrict__ v_att, const float* __restrict__ rng,
    float* __restrict__ s_tab) {
    const int b = blockIdx.x >> 4;
    const int tp0 = (blockIdx.x & 15) * 8;
    const int lane = threadIdx.x & 63, wave = threadIdx.x >> 6;
    const float glo = rng[0], gstep = rng[1];
    float e8[8][8];
    #pragma unroll
    for (int r = 0; r < 8; ++r) {
        uint4 ev = *(const uint4*)(ep_bf + ((size_t)(b * T_ + tp0 + r)) * A_ + lane * 8);
        e8[r][0] = bflo(ev.x); e8[r][1] = bfhi(ev.x);
        e8[r][2] = bflo(ev.y); e8[r][3] = bfhi(ev.y);
        e8[r][4] = bflo(ev.z); e8[r][5] = bfhi(ev.z);
        e8[r][6] = bflo(ev.w); e8[r][7] = bfhi(ev.w);
    }
    float v8[8];
    *(float4*)&v8[0] = *(const float4*)(v_att + lane * 8);
    *(float4*)&v8[4] = *(const float4*)(v_att + lane * 8 + 4);
    for (int k = wave; k < KS_; k += 4) {
        const float x = glo + (float)k * gstep;
        float u = fminf(fmaxf((x - LO_) * IDT_, 0.0f), (float)NS_ - 1.001f);
        const int i0 = (int)u;
        const float fr = u - (float)i0;
        const float* qa = qT + (size_t)i0 * A_ + lane * 8;
        const float* qb = qa + A_;
        float q8[8];
        {
            float4 la0 = *(const float4*)(qa);
            float4 la1 = *(const float4*)(qa + 4);
            float4 lb0 = *(const float4*)(qb);
            float4 lb1 = *(const float4*)(qb + 4);
            q8[0] = la0.x + fr * (lb0.x - la0.x);
            q8[1] = la0.y + fr * (lb0.y - la0.y);
            q8[2] = la0.z + fr * (lb0.z - la0.z);
            q8[3] = la0.w + fr * (lb0.w - la0.w);
            q8[4] = la1.x + fr * (lb1.x - la1.x);
            q8[5] = la1.y + fr * (lb1.y - la1.y);
            q8[6] = la1.z + fr * (lb1.z - la1.z);
            q8[7] = la1.w + fr * (lb1.w - la1.w);
        }
        float s[8] = {};
        #pragma unroll
        for (int r = 0; r < 8; ++r)
            #pragma unroll
            for (int j = 0; j < 8; ++j)
                s[r] += tanh_fast(q8[j] + e8[r][j]) * v8[j];
        #pragma unroll
        for (int r = 0; r < 8; ++r) {
            float xsum = s[r];
            #pragma unroll
            for (int off = 32; off; off >>= 1) xsum += __shfl_xor(xsum, off);
            if (lane == 0) s_tab[((size_t)(b * T_ + tp0 + r)) * KS_ + k] = xsum;
        }
    }
}

// ---------------------------------------------------------------------------
// Full xin recurrence + softmax weight output
__global__ __launch_bounds__(64) void k_chain(
    const float* __restrict__ s_tab, const float* __restrict__ e2,
    const float* __restrict__ xd, const float* __restrict__ rng,
    float* __restrict__ xinA, unsigned int* __restrict__ w_h32) {
    const int b = blockIdx.x;
    const int lane = threadIdx.x;
    const float glo = rng[0], gistep = rng[2];
    const int tpA = 2 * lane, tpB = 2 * lane + 1;
    const float e20 = e2[b * T_ + tpA];
    const float e21 = e2[b * T_ + tpB];
    const float* st0 = s_tab + ((size_t)b * T_ + tpA) * KS_;
    const float* st1 = s_tab + ((size_t)b * T_ + tpB) * KS_;
    float xin = xd[b * T_];
    for (int t = 0; t < T_; ++t) {
        if (lane == 0) xinA[t * B_ + b] = xin;
        float u = (xin - glo) * gistep;
        u = fminf(fmaxf(u, 0.0f), (float)KS_ - 1.001f);
        int k0 = (int)u; float fr = u - (float)k0;
        float a0 = st0[k0], a1 = st0[k0 + 1];
        float c0 = st1[k0], c1 = st1[k0 + 1];
        float s0 = a0 + fr * (a1 - a0);
        float s1 = c0 + fr * (c1 - c0);
        float m = fmaxf(s0, s1);
        #pragma unroll
        for (int off = 32; off; off >>= 1) m = fmaxf(m, __shfl_xor(m, off));
        float ex0 = __builtin_amdgcn_exp2f(1.44269504089f * (s0 - m));
        float ex1 = __builtin_amdgcn_exp2f(1.44269504089f * (s1 - m));
        float num = ex0 * e20 + ex1 * e21;
        float den = ex0 + ex1;
        #pragma unroll
        for (int off = 32; off; off >>= 1) {
            num += __shfl_xor(num, off);
            den += __shfl_xor(den, off);
        }
        float rdn = __builtin_amdgcn_rcpf(den);
        union { _Float16 h[2]; unsigned int u32; } cv;
        cv.h[0] = (_Float16)(ex0 * rdn);
        cv.h[1] = (_Float16)(ex1 * rdn);
        w_h32[((size_t)b * T_ + t) * 64 + lane] = cv.u32;
        if (t + 1 < T_) xin = xd[b * T_ + t + 1] + num * rdn;
    }
}

// ---------------------------------------------------------------------------
// ctx MFMA GEMM (f16)
__global__ __launch_bounds__(256) void k_ctxmm(
    const _Float16* __restrict__ w_h, const _Float16* __restrict__ encT,
    unsigned short* __restrict__ ctx_bf) {
    const int b = blockIdx.x >> 2;
    const int n0 = (blockIdx.x & 3) * 128;
    const int lane = threadIdx.x & 63, wave = threadIdx.x >> 6;
    const int wm = wave >> 1, wn = wave & 1;
    const int frow = lane & 15, koct = (lane >> 4) * 8;
    const _Float16* Ab = w_h + ((size_t)b * T_ + wm * 64 + frow) * T_ + koct;
    const _Float16* Bb = encT + ((size_t)(b * U_ + n0 + wn * 64 + frow)) * T_ + koct;
    f32x4 acc[4][4] = {};
    #pragma unroll
    for (int ks = 0; ks < 4; ++ks) {
        f16x8 a[4], bb[4];
        #pragma unroll
        for (int m = 0; m < 4; ++m) a[m] = *(const f16x8*)(Ab + (size_t)m * 16 * T_ + ks * 32);
        #pragma unroll
        for (int n = 0; n < 4; ++n) bb[n] = *(const f16x8*)(Bb + (size_t)n * 16 * T_ + ks * 32);
        #pragma unroll
        for (int m = 0; m < 4; ++m)
            #pragma unroll
            for (int n = 0; n < 4; ++n)
                acc[m][n] = __builtin_amdgcn_mfma_f32_16x16x32_f16(a[m], bb[n], acc[m][n], 0, 0, 0);
    }
    #pragma unroll
    for (int m = 0; m < 4; ++m)
        #pragma unroll
        for (int n = 0; n < 4; ++n)
            #pragma unroll
            for (int reg = 0; reg < 4; ++reg) {
                int t = wm * 64 + m * 16 + (lane >> 4) * 4 + reg;
                int u = n0 + wn * 64 + n * 16 + (lane & 15);
                ctx_bf[((size_t)t * B_ + b) * U_ + u] = f2bf(acc[m][n][reg]);
            }
}

// ---------------------------------------------------------------------------
// zc2[tb][col] = (ctx_bf @ Wf2T)[tb][col] + lerp(zhT_h, xin[tb]) + bf[col], f16.
__global__ __launch_bounds__(256) void k_zc(
    const unsigned short* __restrict__ ctx_bf,
    const unsigned short* __restrict__ Wf2T, int ldb,
    const _Float16* __restrict__ zhT_h, const float* __restrict__ xinA,
    const float* __restrict__ bfv, _Float16* __restrict__ zc2) {
    const int n0 = blockIdx.x * 128;
    const int m0 = blockIdx.y * 128;
    const int lane = threadIdx.x & 63, wave = threadIdx.x >> 6;
    const int wm = wave >> 1, wn = wave & 1;
    const int frow = lane & 15, koct = (lane >> 4) * 8;
    const unsigned short* Ab = ctx_bf + (size_t)(m0 + wm * 64 + frow) * 512 + koct;
    const unsigned short* Bb = Wf2T + (size_t)(n0 + wn * 64 + frow) * ldb + koct;
    f32x4 acc[4][4] = {};
    for (int ks = 0; ks < 16; ++ks) {
        bf16x8 a[4], bb[4];
        #pragma unroll
        for (int m = 0; m < 4; ++m) a[m] = *(const bf16x8*)(Ab + (size_t)m * 16 * 512 + ks * 32);
        #pragma unroll
        for (int n = 0; n < 4; ++n) bb[n] = *(const bf16x8*)(Bb + (size_t)n * 16 * ldb + ks * 32);
        #pragma unroll
        for (int m = 0; m < 4; ++m)
            #pragma unroll
            for (int n = 0; n < 4; ++n)
                acc[m][n] = __builtin_amdgcn_mfma_f32_16x16x32_bf16(a[m], bb[n], acc[m][n], 0, 0, 0);
    }
    #pragma unroll
    for (int m = 0; m < 4; ++m)
        #pragma unroll
        for (int reg = 0; reg < 4; ++reg) {
            const int r = m0 + wm * 64 + m * 16 + (lane >> 4) * 4 + reg;
            const float xv = xinA[r];
            float u = fminf(fmaxf((xv - LO_) * IDT_, 0.0f), (float)NS_ - 1.001f);
            const int i0 = (int)u;
            const float fr = u - (float)i0;
            const _Float16* zh0 = zhT_h + (size_t)i0 * G_;
            const _Float16* zh1 = zh0 + G_;
            #pragma unroll
            for (int n = 0; n < 4; ++n) {
                const int col = n0 + wn * 64 + n * 16 + (lane & 15);
                const float lo = (float)zh0[col];
                const float val = acc[m][n][reg] + lo + fr * ((float)zh1[col] - lo) + bfv[col];
                zc2[(size_t)r * G_ + col] = (_Float16)val;
            }
        }
}

// ---------------------------------------------------------------------------
// Final LSTM step (relaunched per j). K=512 (h only); ctx+zhT+bf pre-fused in
// zc2. Grid (32 d-tiles, 8 r-tiles), 256 threads (4 waves).
__global__ __launch_bounds__(256) void k_frec3(
    const unsigned short* __restrict__ hin, unsigned short* __restrict__ hout,
    const unsigned short* __restrict__ UfT, const _Float16* __restrict__ zc2,
    float* __restrict__ c_f, float* __restrict__ out, int j) {
    __shared__ unsigned short As[32][520];   // 33,280 B
    __shared__ float zs[32 * 68];            //  8,704 B
    const int tid = threadIdx.x;
    const int lane = tid & 63, wave = tid >> 6;
    const int wr = wave >> 1, wc = wave & 1;
    const int d0 = blockIdx.x * 16;
    const int r0 = blockIdx.y * 32;
    // ---- stage A: 32 rows x 512 (h), once
    #pragma unroll
    for (int p = 0; p < 8; ++p) {
        int idx = p * 256 + tid;
        int row = idx >> 6, seg = idx & 63;
        int k = seg * 8;
        uint4 v = *(const uint4*)(hin + (size_t)(r0 + row) * 512 + k);
        *(uint4*)&As[row][k] = v;
    }
    __syncthreads();
    // ---- MFMA: wave owns rows [16wr,+16) x z-cols [32wc,+32)
    const int arow = 16 * wr + (lane & 15);
    const int koct = (lane >> 4) * 8;
    const int cl = lane & 15;
    const unsigned short* Bp0 = UfT + ((size_t)(((2 * wc) << 9) + d0 + cl)) * 512;
    const unsigned short* Bp1 = UfT + ((size_t)(((2 * wc + 1) << 9) + d0 + cl)) * 512;
    f32x4 acc0 = {0.f, 0.f, 0.f, 0.f};
    f32x4 acc1 = {0.f, 0.f, 0.f, 0.f};
    #pragma unroll
    for (int kc = 0; kc < 8; ++kc) {
        #pragma unroll
        for (int ks = 0; ks < 2; ++ks) {
            const int kw = kc * 64 + ks * 32 + koct;
            bf16x8 af = *(const bf16x8*)&As[arow][kw];
            bf16x8 b0 = *(const bf16x8*)(Bp0 + kw);
            bf16x8 b1 = *(const bf16x8*)(Bp1 + kw);
            acc0 = __builtin_amdgcn_mfma_f32_16x16x32_bf16(af, b0, acc0, 0, 0, 0);
            acc1 = __builtin_amdgcn_mfma_f32_16x16x32_bf16(af, b1, acc1, 0, 0, 0);
        }
    }
    // ---- spill z to LDS
    {
        const int srow = 16 * wr + (lane >> 4) * 4;
        const int scol = 32 * wc + (lane & 15);
        #pragma unroll
        for (int reg = 0; reg < 4; ++reg) {
            zs[(srow + reg) * 68 + scol] = acc0[reg];
            zs[(srow + reg) * 68 + scol + 16] = acc1[reg];
        }
    }
    __syncthreads();
    // ---- fused gate epilogue
    #pragma unroll
    for (int p = 0; p < 2; ++p) {
        const int it = p * 256 + tid;
        const int r = it >> 4, dd = it & 15;
        const int i = r0 + r, d = d0 + dd;
        const size_t tb = (size_t)(i >> 1) * B_ + ((i & 1) << 7) + j;
        const _Float16* zcrow = zc2 + tb * G_;
        float zg4[4];
        zg4[0] = zs[r * 68 + dd]      + (float)zcrow[d];
        zg4[1] = zs[r * 68 + 16 + dd] + (float)zcrow[512 + d];
        zg4[2] = zs[r * 68 + 32 + dd] + (float)zcrow[1024 + d];
        zg4[3] = zs[r * 68 + 48 + dd] + (float)zcrow[1536 + d];
        const float co = c_f[(size_t)i * D_ + d];
        const float cn = sigf(zg4[1]) * co + sigf(zg4[0]) * tanh_fast(zg4[2]);
        const float hn = sigf(zg4[3]) * tanh_fast(cn);
        c_f[(size_t)i * D_ + d] = cn;
        hout[(size_t)i * D_ + d] = f2bf(hn);
        out[((size_t)i * T_ + j) * D_ + d] = hn;
    }
}

// ---------------------------------------------------------------------------
extern "C" void kernel_launch(void* const* d_in, const int* in_sizes, int n_in,
                              void* d_out, int out_size, void* d_ws, size_t ws_size,
                              hipStream_t stream) {
    const float* inputs = (const float*)d_in[0];
    const float* enc    = (const float*)d_in[1];
    const float* Wd     = (const float*)d_in[2];
    const float* bd     = (const float*)d_in[3];
    const float* W0     = (const float*)d_in[4];
    const float* b0     = (const float*)d_in[6];
    const float* W1     = (const float*)d_in[7];
    const float* b1     = (const float*)d_in[9];
    const float* Wq     = (const float*)d_in[10];
    const float* Wk     = (const float*)d_in[11];
    const float* v_att  = (const float*)d_in[12];
    const float* Wf     = (const float*)d_in[13];
    const float* Uf     = (const float*)d_in[14];
    const float* bf     = (const float*)d_in[15];
    float* out = (float*)d_out;

    float* ws = (float*)d_ws;
    // ---- layout (f32 slots). zc2 overlays all early-phase-dead buffers.
    _Float16* zc2 = (_Float16*)(ws);                       // 33,554,432 S (written late)
    unsigned short* enc_bf = (unsigned short*)(ws);        //  8,388,608 S
    unsigned short* ep_bf  = (unsigned short*)(ws + 8388608);   // 8,388,608
    _Float16*       encT_h = (_Float16*)(ws + 16777216);        // 8,388,608
    float* s_tab   = ws + 25165824;                             // 2,097,152
    _Float16* w_h  = (_Float16*)(ws + 27262976);                // 2,097,152
    float* qT      = ws + 29360128;                             // 1,048,576
    float* h0T     = ws + 30408704;                             // 1,048,576
    unsigned short* h0T_bf = (unsigned short*)(ws + 31457280);  //   524,288
    unsigned short* W1T    = (unsigned short*)(ws + 31981568);  //   524,288
    unsigned short* WqT    = (unsigned short*)(ws + 32505856);  //   262,144
    // ---- beyond zc2 region:
    unsigned short* ctx_bf = (unsigned short*)(ws + 33554432);  // 8,388,608 (live til k_zc)
    _Float16* zhT_h = (_Float16*)(ws + 41943040);               // 2,097,152 slots (f16)
    float* h1c1T   = ws + 46137344;                             // 2,097,152
    unsigned short* h1c1T_bf = (unsigned short*)(ws + 48234496);// 1,048,576
    unsigned short* WfT    = (unsigned short*)(ws + 49283072);  // 1,048,576 (Wf2T = +512)
    unsigned short* UfT    = (unsigned short*)(ws + 50331648);  //   524,288
    unsigned short* WkT    = (unsigned short*)(ws + 50855936);  //   131,072
    float* e2      = ws + 50987008;                             //    32,768
    float* xd      = ws + 51019776;                             //    32,768
    float* xinA    = ws + 51052544;                             //    32,768
    unsigned short* h_bf = (unsigned short*)(ws + 51085312);    //   131,072 (2 bufs)
    float* c_f     = ws + 51216384;                             //   131,072
    float* rng     = ws + 51347456;                             //        16
    // z1T (2048x2048 f32) aliases ctx_bf region (dead before k_ctxmm writes it)
    float* z1T = (float*)ctx_bf;

    // ---- one-time tables (MFMA GEMMs) & conversions
    k_h0build<<<dim3(NS_ * D_ / 1024), 256, 0, stream>>>(W0, b0, h0T);
    k_cvt_bf16<<<dim3(512), 256, 0, stream>>>(h0T, h0T_bf);
    k_wT<<<dim3(32, 8), 256, 0, stream>>>(W1, W1T, 512, G_);
    k_mm<<<dim3(16, 16), 256, 0, stream>>>(h0T_bf, W1T, z1T, 512, G_);
    k_gates1<<<dim3(NS_ * D_ / 1024), 256, 0, stream>>>(z1T, b1, h1c1T);
    k_cvt_bf16<<<dim3(1024), 256, 0, stream>>>(h1c1T, h1c1T_bf);
    k_wT<<<dim3(8, 16), 256, 0, stream>>>(Wq, WqT, 1024, A_);
    k_mm<<<dim3(4, 16), 256, 0, stream>>>(h1c1T_bf, WqT, qT, 1024, A_);
    k_wT<<<dim3(32, 16), 256, 0, stream>>>(Wf, WfT, 1024, G_);
    k_mmh<<<dim3(16, 16), 256, 0, stream>>>(h1c1T_bf, WfT, zhT_h, 1024, G_);
    k_wT<<<dim3(32, 8), 256, 0, stream>>>(Uf, UfT, 512, G_);
    k_encT<<<dim3(B_ * 4), 256, 0, stream>>>(enc, encT_h, enc_bf);
    k_wkT<<<dim3(256), 256, 0, stream>>>(Wk, WkT);
    k_epmm<<<dim3(4, 256), 256, 0, stream>>>(enc_bf, WkT, ep_bf);
    k_xd<<<dim3(B_ * T_ / 256), 256, 0, stream>>>(inputs, Wd, bd, xd);
    k_e2<<<dim3(B_ * T_ / 4), 256, 0, stream>>>(enc, Wd + F_, e2);
    k_bounds<<<dim3(1), 256, 0, stream>>>(xd, e2, rng);

    hipMemsetAsync(h_bf, 0, (size_t)B_ * D_ * sizeof(unsigned short), stream);
    hipMemsetAsync(c_f, 0, (size_t)B_ * D_ * sizeof(float), stream);

    // ---- decoder: score table -> scalar chain (+weights) -> ctx GEMM
    k_stab<<<dim3(B_ * 16), 256, 0, stream>>>(qT, ep_bf, v_att, rng, s_tab);
    k_chain<<<dim3(B_), 64, 0, stream>>>(s_tab, e2, xd, rng, xinA, (unsigned int*)w_h);
    k_ctxmm<<<dim3(B_ * 4), 256, 0, stream>>>(w_h, encT_h, ctx_bf);

    // ---- hoist ctx@Wf2 + zhT-interp + bf out of the recurrence (one GEMM)
    k_zc<<<dim3(16, 256), 256, 0, stream>>>(ctx_bf, WfT + 512, 1024, zhT_h, xinA,
                                            bf, zc2);

    // ---- final LSTM: 128 fused MFMA steps (K=512, h double-buffered)
    for (int j = 0; j < T_; ++j) {
        const unsigned short* hin = h_bf + (size_t)(j & 1) * (B_ * D_);
        unsigned short* hout = h_bf + (size_t)((j + 1) & 1) * (B_ * D_);
        k_frec3<<<dim3(32, 8), 256, 0, stream>>>(hin, hout, UfT, zc2, c_f, out, j);
    }
}